// Round 3
// baseline (699.013 us; speedup 1.0000x reference)
//
#include <hip/hip_runtime.h>
#include <stdint.h>

typedef __attribute__((ext_vector_type(8))) short bf16x8;
typedef __attribute__((ext_vector_type(4))) float f32x4;

__device__ __forceinline__ float b2f(short h) {
  return __uint_as_float(((unsigned)(unsigned short)h) << 16);
}
__device__ __forceinline__ short f2b(float f) {
  unsigned u = __float_as_uint(f);
  u += 0x7fffu + ((u >> 16) & 1u);
  return (short)(u >> 16);
}

// chunk-swizzle (in shorts): XOR the 8-short chunk index with (r>>1)&3.
// Per 8-lane LDS service group this spreads (row parity, chunk) over all 8
// bank-quads -> conflict-free ds_read_b128 / ds_write_b128.
__device__ __forceinline__ int swz(int r) { return (r & 6) << 2; }

// async global->LDS, 16 B per lane (global_load_lds_dwordx4)
__device__ __forceinline__ void glds16(const void* g, void* l) {
  __builtin_amdgcn_global_load_lds(
      (const __attribute__((address_space(1))) void*)g,
      (__attribute__((address_space(3))) void*)l, 16, 0, 0);
}

// XCD-aware decode: 1-D grid; the C col-tiles of one row-strip land on one XCD
// (consecutive slots), row-strips partitioned across XCDs. Bijective for
// total = 8 * RSX * C, RSX = row-strips per XCD, RPZ = row-strips per z.
__device__ __forceinline__ void xcd_decode(int C, int RSX, int RPZ,
                                           int& z, int& rowB, int& colB) {
  int id = blockIdx.x;
  int xcd = id & 7, slot = id >> 3;
  int rs = xcd * RSX + slot / C;
  colB = (slot % C) * 128;
  z = rs / RPZ;
  rowB = (rs % RPZ) * 128;
}

// ---------------- one-shot fp32 -> (bf16 hi, bf16 lo) split, 8 elem/thread ----
__global__ __launch_bounds__(256) void cvt_kernel(
    const float* __restrict__ S0, short* __restrict__ H0, short* __restrict__ L0,
    const float* __restrict__ S1, short* __restrict__ H1, short* __restrict__ L1,
    const float* __restrict__ S2, short* __restrict__ H2, short* __restrict__ L2,
    int n0, int n1, int n2) {
  int g = blockIdx.x * 256 + threadIdx.x;
  const float* s;
  short* h;
  short* l;
  if (g < n0) {
    s = S0 + (size_t)g * 8;
    h = H0 + (size_t)g * 8;
    l = L0 + (size_t)g * 8;
  } else if (g < n0 + n1) {
    size_t t = (size_t)(g - n0);
    s = S1 + t * 8;
    h = H1 + t * 8;
    l = L1 + t * 8;
  } else {
    size_t t = (size_t)(g - n0 - n1);
    s = S2 + t * 8;
    h = H2 + t * 8;
    l = L2 + t * 8;
  }
  float4 v0 = *reinterpret_cast<const float4*>(s);
  float4 v1 = *reinterpret_cast<const float4*>(s + 4);
  float vv[8] = {v0.x, v0.y, v0.z, v0.w, v1.x, v1.y, v1.z, v1.w};
  bf16x8 th, tl;
#pragma unroll
  for (int j = 0; j < 8; ++j) {
    short hh = f2b(vv[j]);
    th[j] = hh;
    tl[j] = f2b(vv[j] - b2f(hh));
  }
  *reinterpret_cast<bf16x8*>(h) = th;
  *reinterpret_cast<bf16x8*>(l) = tl;
}

// ---------------- row sums of P (bf16, 2048 cols) -> store 1/sum ----------------
__global__ __launch_bounds__(256) void rowsum_kernel(const short* __restrict__ P,
                                                     float* __restrict__ invL) {
  int wave = threadIdx.x >> 6, lane = threadIdx.x & 63;
  size_t row = (size_t)blockIdx.x * 4 + wave;
  const short* p = P + row * 2048;
  float s = 0.f;
#pragma unroll
  for (int it = 0; it < 4; ++it) {
    bf16x8 x = *reinterpret_cast<const bf16x8*>(&p[it * 512 + lane * 8]);
#pragma unroll
    for (int j = 0; j < 8; ++j) s += b2f(x[j]);
  }
#pragma unroll
  for (int m = 32; m; m >>= 1) s += __shfl_xor(s, m);
  if (lane == 0) invL[row] = 1.0f / s;
}

// =================================================================================
// projg: C = A @ B^T + bias with 3-pass split precision (ah*bh + al*bh + ah*bl),
// all operands pre-converted bf16 planes, glds staging with pre-swizzled source.
// =================================================================================
template <bool LO>
__global__ __launch_bounds__(256) void projg_kernel(
    const short* __restrict__ Ah, const short* __restrict__ Al,
    const short* __restrict__ Bh, const short* __restrict__ Bl,
    const float* __restrict__ bias,
    short* __restrict__ Ch, short* __restrict__ Cl) {
  __shared__ alignas(16) short AsH[128 * 32];
  __shared__ alignas(16) short AsL[128 * 32];
  __shared__ alignas(16) short BsH[128 * 32];
  __shared__ alignas(16) short BsL[128 * 32];
  const int tid = threadIdx.x;
  int z, rowBase, colBase;
  xcd_decode(6, 16, 128, z, rowBase, colBase);  // total 768 = 8*16*6, z always 0
  (void)z;
  const int lane = tid & 63;
  const int ln = lane & 15;
  const int qd = lane >> 4;
  const int w = tid >> 6;
  const int wr = w >> 1, wc = w & 1;

  f32x4 acc[4][4];
#pragma unroll
  for (int i = 0; i < 4; ++i)
#pragma unroll
    for (int j = 0; j < 4; ++j) acc[i][j] = 0.f;

  for (int kb = 0; kb < 768; kb += 32) {
#pragma unroll
    for (int q = 0; q < 2; ++q) {
      int c = q * 256 + tid;
      int r = c >> 2;
      int k0 = ((c & 3) << 3) ^ swz(r);  // pre-swizzled global chunk
      size_t ao = (size_t)(rowBase + r) * 768 + kb + k0;
      size_t bo = (size_t)(colBase + r) * 768 + kb + k0;
      glds16(&Ah[ao], &AsH[c * 8]);
      glds16(&Al[ao], &AsL[c * 8]);
      glds16(&Bh[bo], &BsH[c * 8]);
      glds16(&Bl[bo], &BsL[c * 8]);
    }
    __syncthreads();
    bf16x8 ah[4], bh[4], t[4];
#pragma unroll
    for (int rt = 0; rt < 4; ++rt) {
      int m = wr * 64 + rt * 16 + ln;
      ah[rt] = *reinterpret_cast<const bf16x8*>(&AsH[m * 32 + ((qd * 8) ^ swz(m))]);
    }
#pragma unroll
    for (int ct = 0; ct < 4; ++ct) {
      int n = wc * 64 + ct * 16 + ln;
      bh[ct] = *reinterpret_cast<const bf16x8*>(&BsH[n * 32 + ((qd * 8) ^ swz(n))]);
    }
#pragma unroll
    for (int rt = 0; rt < 4; ++rt)
#pragma unroll
      for (int ct = 0; ct < 4; ++ct)
        acc[rt][ct] = __builtin_amdgcn_mfma_f32_16x16x32_bf16(ah[rt], bh[ct], acc[rt][ct], 0, 0, 0);
#pragma unroll
    for (int rt = 0; rt < 4; ++rt) {
      int m = wr * 64 + rt * 16 + ln;
      t[rt] = *reinterpret_cast<const bf16x8*>(&AsL[m * 32 + ((qd * 8) ^ swz(m))]);
    }
#pragma unroll
    for (int rt = 0; rt < 4; ++rt)
#pragma unroll
      for (int ct = 0; ct < 4; ++ct)
        acc[rt][ct] = __builtin_amdgcn_mfma_f32_16x16x32_bf16(t[rt], bh[ct], acc[rt][ct], 0, 0, 0);
#pragma unroll
    for (int ct = 0; ct < 4; ++ct) {
      int n = wc * 64 + ct * 16 + ln;
      t[ct] = *reinterpret_cast<const bf16x8*>(&BsL[n * 32 + ((qd * 8) ^ swz(n))]);
    }
#pragma unroll
    for (int rt = 0; rt < 4; ++rt)
#pragma unroll
      for (int ct = 0; ct < 4; ++ct)
        acc[rt][ct] = __builtin_amdgcn_mfma_f32_16x16x32_bf16(ah[rt], t[ct], acc[rt][ct], 0, 0, 0);
    __syncthreads();
  }

#pragma unroll
  for (int rt = 0; rt < 4; ++rt) {
    int row0 = rowBase + wr * 64 + rt * 16 + qd * 4;
#pragma unroll
    for (int ct = 0; ct < 4; ++ct) {
      int col = colBase + wc * 64 + ct * 16 + ln;
      float bb = bias[col];
      f32x4 a = acc[rt][ct];
#pragma unroll
      for (int r = 0; r < 4; ++r) {
        float val = a[r] + bb;
        short h = f2b(val);
        Ch[(size_t)(row0 + r) * 768 + col] = h;
        if constexpr (LO) Cl[(size_t)(row0 + r) * 768 + col] = f2b(val - b2f(h));
      }
    }
  }
}

// =================================================================================
// sim2: P = exp(vp_hi*(lp_hi+lp_lo)^T - 20), fused 2 products per K-tile.
// glds staging with pre-swizzled source.
// =================================================================================
__global__ __launch_bounds__(256) void sim2_kernel(const short* __restrict__ vp,
                                                   const short* __restrict__ lph,
                                                   const short* __restrict__ lpl,
                                                   short* __restrict__ P) {
  __shared__ alignas(16) short As[128 * 32];
  __shared__ alignas(16) short Bh[128 * 32];
  __shared__ alignas(16) short Bl[128 * 32];
  const int tid = threadIdx.x;
  int z, rowBase, colBase;
  xcd_decode(16, 16, 16, z, rowBase, colBase);  // total 2048 = 8*16*16
  const short* Az = vp + (size_t)z * 2048 * 768;
  const short* B0 = lph + (size_t)z * 2048 * 768;
  const short* B1 = lpl + (size_t)z * 2048 * 768;
  const int lane = tid & 63;
  const int ln = lane & 15;
  const int qd = lane >> 4;
  const int w = tid >> 6;
  const int wr = w >> 1, wc = w & 1;

  f32x4 acc[4][4];
#pragma unroll
  for (int i = 0; i < 4; ++i)
#pragma unroll
    for (int j = 0; j < 4; ++j) acc[i][j] = 0.f;

  for (int kb = 0; kb < 768; kb += 32) {
#pragma unroll
    for (int q = 0; q < 2; ++q) {
      int c = q * 256 + tid;
      int r = c >> 2;
      int k0 = ((c & 3) << 3) ^ swz(r);
      glds16(&Az[(size_t)(rowBase + r) * 768 + kb + k0], &As[c * 8]);
      glds16(&B0[(size_t)(colBase + r) * 768 + kb + k0], &Bh[c * 8]);
      glds16(&B1[(size_t)(colBase + r) * 768 + kb + k0], &Bl[c * 8]);
    }
    __syncthreads();
    bf16x8 af[4], bf[4];
#pragma unroll
    for (int rt = 0; rt < 4; ++rt) {
      int m = wr * 64 + rt * 16 + ln;
      af[rt] = *reinterpret_cast<const bf16x8*>(&As[m * 32 + ((qd * 8) ^ swz(m))]);
    }
#pragma unroll
    for (int ct = 0; ct < 4; ++ct) {
      int n = wc * 64 + ct * 16 + ln;
      bf[ct] = *reinterpret_cast<const bf16x8*>(&Bh[n * 32 + ((qd * 8) ^ swz(n))]);
    }
#pragma unroll
    for (int rt = 0; rt < 4; ++rt)
#pragma unroll
      for (int ct = 0; ct < 4; ++ct)
        acc[rt][ct] = __builtin_amdgcn_mfma_f32_16x16x32_bf16(af[rt], bf[ct], acc[rt][ct], 0, 0, 0);
#pragma unroll
    for (int ct = 0; ct < 4; ++ct) {
      int n = wc * 64 + ct * 16 + ln;
      bf[ct] = *reinterpret_cast<const bf16x8*>(&Bl[n * 32 + ((qd * 8) ^ swz(n))]);
    }
#pragma unroll
    for (int rt = 0; rt < 4; ++rt)
#pragma unroll
      for (int ct = 0; ct < 4; ++ct)
        acc[rt][ct] = __builtin_amdgcn_mfma_f32_16x16x32_bf16(af[rt], bf[ct], acc[rt][ct], 0, 0, 0);
    __syncthreads();
  }

  short* Pz = P + (size_t)z * 2048 * 2048;
#pragma unroll
  for (int rt = 0; rt < 4; ++rt) {
    int row0 = rowBase + wr * 64 + rt * 16 + qd * 4;
#pragma unroll
    for (int ct = 0; ct < 4; ++ct) {
      int col = colBase + wc * 64 + ct * 16 + ln;
      f32x4 a = acc[rt][ct];
#pragma unroll
      for (int r = 0; r < 4; ++r)
        Pz[(size_t)(row0 + r) * 2048 + col] = f2b(__expf(a[r] - 20.0f));
    }
  }
}

// =================================================================================
// gemm_k: C[m,n] = sum_k A[m,k]*B[n,k], plain bf16. Plain operands via glds
// (pre-swizzled source). TA/TB: operand given as [K,M]/[K,N] -> register-
// transpose staging (swizzled write). SB: scale B by invL[k]. BF32: B fp32.
// DUALA: A split 768|768.
// MODE 2: bf16 = acc*invL[row]; MODE 3: bf16 = acc; MODE 4: fp32 = acc+bias[col]
// =================================================================================
template <int MODE, bool TA, bool TB, bool SB, bool BF32, bool DUALA>
__global__ __launch_bounds__(256) void gemm_k(const short* __restrict__ A,
                                              const short* __restrict__ A2,
                                              const void* __restrict__ B,
                                              void* __restrict__ C,
                                              const float* __restrict__ bias,
                                              const float* __restrict__ invL,
                                              int C_, int RSX_, int RPZ_,
                                              int K, int ldA, int ldB, int ldC,
                                              long sA, long sB, long sC, long sL) {
  __shared__ alignas(16) short As[128 * 32];
  __shared__ alignas(16) short Bs[128 * 32];
  const int tid = threadIdx.x;
  int z, rowBase, colBase;
  xcd_decode(C_, RSX_, RPZ_, z, rowBase, colBase);
  const short* Az = A + (size_t)z * sA;
  const float* Lz = invL ? (invL + (size_t)z * sL) : nullptr;
  const int lane = tid & 63;
  const int ln = lane & 15;
  const int qd = lane >> 4;
  const int w = tid >> 6;
  const int wr = w >> 1, wc = w & 1;
  constexpr bool GA = !TA;

  f32x4 acc[4][4];
#pragma unroll
  for (int i = 0; i < 4; ++i)
#pragma unroll
    for (int j = 0; j < 4; ++j) acc[i][j] = 0.f;

  for (int kb = 0; kb < K; kb += 32) {
    if constexpr (GA) {
#pragma unroll
      for (int q = 0; q < 2; ++q) {
        int c = q * 256 + tid;
        int r = c >> 2;
        int k0 = ((c & 3) << 3) ^ swz(r);
        int kk = kb + k0;
        const short* src;
        if constexpr (DUALA) {
          src = (kk < 768) ? &Az[(size_t)(rowBase + r) * 768 + kk]
                           : &A2[(size_t)(rowBase + r) * 768 + kk - 768];
        } else {
          src = &Az[(size_t)(rowBase + r) * ldA + kk];
        }
        glds16(src, &As[c * 8]);
      }
    } else {
#pragma unroll
      for (int q = 0; q < 2; ++q) {
        int task = q * 256 + tid;
        int m = task & 127;
        int kc = (task >> 7) << 3;
        bf16x8 t;
#pragma unroll
        for (int s = 0; s < 8; ++s)
          t[s] = Az[(size_t)(kb + kc + s) * ldA + rowBase + m];
        *reinterpret_cast<bf16x8*>(&As[m * 32 + (kc ^ swz(m))]) = t;
      }
    }
    if constexpr (TB) {
      const short* Bz = (const short*)B + (size_t)z * sB;
#pragma unroll
      for (int q = 0; q < 2; ++q) {
        int task = q * 256 + tid;
        int n = task & 127;
        int kc = (task >> 7) << 3;
        bf16x8 t;
#pragma unroll
        for (int s = 0; s < 8; ++s) {
          short v = Bz[(size_t)(kb + kc + s) * ldB + colBase + n];
          if constexpr (SB) v = f2b(b2f(v) * Lz[kb + kc + s]);
          t[s] = v;
        }
        *reinterpret_cast<bf16x8*>(&Bs[n * 32 + (kc ^ swz(n))]) = t;
      }
    } else if constexpr (BF32) {
      const float* Bf = (const float*)B + (size_t)z * sB;
#pragma unroll
      for (int q = 0; q < 2; ++q) {
        int c = q * 256 + tid;
        int r = c >> 2;
        int k0 = (c & 3) << 3;
        const float* p = &Bf[(size_t)(colBase + r) * ldB + kb + k0];
        float4 v0 = *reinterpret_cast<const float4*>(p);
        float4 v1 = *reinterpret_cast<const float4*>(p + 4);
        float vv[8] = {v0.x, v0.y, v0.z, v0.w, v1.x, v1.y, v1.z, v1.w};
        bf16x8 t;
#pragma unroll
        for (int s = 0; s < 8; ++s) t[s] = f2b(vv[s]);
        *reinterpret_cast<bf16x8*>(&Bs[r * 32 + (k0 ^ swz(r))]) = t;
      }
    } else {
      const short* Bz = (const short*)B + (size_t)z * sB;
#pragma unroll
      for (int q = 0; q < 2; ++q) {
        int c = q * 256 + tid;
        int r = c >> 2;
        int k0 = ((c & 3) << 3) ^ swz(r);
        glds16(&Bz[(size_t)(colBase + r) * ldB + kb + k0], &Bs[c * 8]);
      }
    }
    __syncthreads();
    bf16x8 af[4], bfv[4];
#pragma unroll
    for (int rt = 0; rt < 4; ++rt) {
      int m = wr * 64 + rt * 16 + ln;
      af[rt] = *reinterpret_cast<const bf16x8*>(&As[m * 32 + ((qd * 8) ^ swz(m))]);
    }
#pragma unroll
    for (int ct = 0; ct < 4; ++ct) {
      int n = wc * 64 + ct * 16 + ln;
      bfv[ct] = *reinterpret_cast<const bf16x8*>(&Bs[n * 32 + ((qd * 8) ^ swz(n))]);
    }
#pragma unroll
    for (int rt = 0; rt < 4; ++rt)
#pragma unroll
      for (int ct = 0; ct < 4; ++ct)
        acc[rt][ct] =
            __builtin_amdgcn_mfma_f32_16x16x32_bf16(af[rt], bfv[ct], acc[rt][ct], 0, 0, 0);
    __syncthreads();
  }

#pragma unroll
  for (int rt = 0; rt < 4; ++rt) {
    int row0 = rowBase + wr * 64 + rt * 16 + qd * 4;
#pragma unroll
    for (int ct = 0; ct < 4; ++ct) {
      int col = colBase + wc * 64 + ct * 16 + ln;
      f32x4 a = acc[rt][ct];
      if constexpr (MODE == 2) {
        short* Co = (short*)C + (size_t)z * sC;
#pragma unroll
        for (int r = 0; r < 4; ++r)
          Co[(size_t)(row0 + r) * ldC + col] = f2b(a[r] * Lz[row0 + r]);
      } else if constexpr (MODE == 3) {
        short* Co = (short*)C + (size_t)z * sC;
#pragma unroll
        for (int r = 0; r < 4; ++r) Co[(size_t)(row0 + r) * ldC + col] = f2b(a[r]);
      } else {  // MODE 4
        float* Co = (float*)C + (size_t)z * sC;
        float bb = bias[col];
#pragma unroll
        for (int r = 0; r < 4; ++r) Co[(size_t)(row0 + r) * ldC + col] = a[r] + bb;
      }
    }
  }
}

extern "C" void kernel_launch(void* const* d_in, const int* in_sizes, int n_in,
                              void* d_out, int out_size, void* d_ws, size_t ws_size,
                              hipStream_t stream) {
  const float* vf = (const float*)d_in[0];
  const float* lf = (const float*)d_in[1];
  const float* Wv = (const float*)d_in[2];
  const float* bv = (const float*)d_in[3];
  const float* Wl = (const float*)d_in[4];
  const float* bl = (const float*)d_in[5];
  const float* Wo = (const float*)d_in[6];
  const float* bo = (const float*)d_in[7];

  constexpr int Bz = 8, L = 2048, D = 768, M = Bz * L, D2 = 2 * D;
  constexpr size_t PLANE = (size_t)M * D;      // 12,582,912 elems
  constexpr size_t WPLANE = (size_t)D * D;     // 589,824 elems

  char* wp = (char*)d_ws;
  auto alloc = [&](size_t bytes) {
    char* p = wp;
    wp += (bytes + 255) & ~(size_t)255;
    return p;
  };
  short* vp_hi = (short*)alloc(PLANE * 2);               // 25.2 MB; -> al after av
  short* P     = (short*)alloc((size_t)Bz * L * L * 2);  // 67.1 MB
  float* invL  = (float*)alloc((size_t)M * 4);           // 64 KB

  // If workspace permits, keep lp planes in ws and write step-6 output
  // directly to d_out (skips the 50 MB trailing memcpy).
  size_t need_direct = (size_t)(wp - (char*)d_ws) + 2 * PLANE * 2 + 512;
  bool direct = ws_size >= need_direct;

  short* lp_hi, *lp_lo;
  if (direct) {
    lp_hi = (short*)alloc(PLANE * 2);
    lp_lo = (short*)alloc(PLANE * 2);
  } else {
    lp_hi = (short*)d_out;
    lp_lo = lp_hi + PLANE;
  }
  short* al      = vp_hi;             // vp_hi dead after step 4
  short* av      = lp_lo;             // lp_lo dead after sim
  float* out_tmp = direct ? (float*)d_out : (float*)P;  // P dead after step 5

  // Transient hi/lo planes live inside the (not-yet-written) P region:
  // fh/fl (feature, 50.3 MB) + 4 weight planes (4.7 MB) = 55.0 MB <= 67.1 MB.
  short* fh  = P;
  short* fl  = P + PLANE;
  short* wvh = P + 2 * PLANE;
  short* wvl = wvh + WPLANE;
  short* wlh = wvl + WPLANE;
  short* wll = wlh + WPLANE;

  constexpr int GF = (int)(PLANE / 8);   // 1,572,864 groups (feature)
  constexpr int GW = (int)(WPLANE / 8);  // 73,728 groups (weight)

  // 1a) convert vision features + both weights (one-shot hi/lo split)
  cvt_kernel<<<dim3((GF + 2 * GW) / 256), 256, 0, stream>>>(
      vf, fh, fl, Wv, wvh, wvl, Wl, wlh, wll, GF, GW, GW);

  // 1b) vision projection: vp_hi = round(Vf @ Wv^T + bv). 768 blocks = 8*16*6
  projg_kernel<false><<<dim3(768), 256, 0, stream>>>(fh, fl, wvh, wvl, bv, vp_hi, nullptr);

  // 1c) convert language features (reuse the same planes)
  cvt_kernel<<<dim3(GF / 256), 256, 0, stream>>>(
      lf, fh, fl, nullptr, nullptr, nullptr, nullptr, nullptr, nullptr, GF, 0, 0);

  // 1d) language projection: lp_hi + lp_lo = split(Lf @ Wl^T + bl)
  projg_kernel<true><<<dim3(768), 256, 0, stream>>>(fh, fl, wlh, wll, bl, lp_hi, lp_lo);

  // 2) P = exp(vp*lp^T - 20). 2048 blocks = 8 * 16 * 16 (overwrites planes)
  sim2_kernel<<<dim3(2048), 256, 0, stream>>>(vp_hi, lp_hi, lp_lo, P);

  // 3) invL
  rowsum_kernel<<<dim3(M / 4), 256, 0, stream>>>(P, invL);

  // 4) aligned_vision = (P @ vp) * invL[row] -> av.  768 blocks = 8 * 16 * 6
  gemm_k<2, false, true, false, false, false><<<dim3(768), 256, 0, stream>>>(
      P, nullptr, vp_hi, av, nullptr, invL, 6, 16, 16, L, L, D, D,
      (long)L * L, (long)L * D, (long)L * D, (long)L);

  // 5) aligned_language = P^T @ (lp * invL[k]) -> al.  768 blocks
  gemm_k<3, true, true, true, false, false><<<dim3(768), 256, 0, stream>>>(
      P, nullptr, lp_hi, al, nullptr, invL, 6, 16, 16, L, L, D, D,
      (long)L * L, (long)L * D, (long)L * D, (long)L);

  // 6) out = [av | al] @ Wo^T + bo (fp32). 768 blocks = 8 * 16 * 6, z=0
  gemm_k<4, false, false, false, true, true><<<dim3(768), 256, 0, stream>>>(
      av, al, Wo, out_tmp, bo, nullptr, 6, 16, 128, D2, D, D2, D, 0, 0, 0, 0);

  // 7) out_tmp -> d_out (only when step 6 couldn't write directly)
  if (!direct)
    hipMemcpyAsync(d_out, out_tmp, (size_t)M * D * 4, hipMemcpyDeviceToDevice, stream);
}

// Round 4
// 657.946 us; speedup vs baseline: 1.0624x; 1.0624x over previous
//
#include <hip/hip_runtime.h>
#include <stdint.h>

typedef __attribute__((ext_vector_type(8))) short bf16x8;
typedef __attribute__((ext_vector_type(4))) float f32x4;

__device__ __forceinline__ float b2f(short h) {
  return __uint_as_float(((unsigned)(unsigned short)h) << 16);
}
__device__ __forceinline__ short f2b(float f) {
  unsigned u = __float_as_uint(f);
  u += 0x7fffu + ((u >> 16) & 1u);
  return (short)(u >> 16);
}

// chunk-swizzle (in shorts): XOR the 8-short chunk index with (r>>1)&3.
__device__ __forceinline__ int swz(int r) { return (r & 6) << 2; }

// async global->LDS, 16 B per lane (global_load_lds_dwordx4)
__device__ __forceinline__ void glds16(const void* g, void* l) {
  __builtin_amdgcn_global_load_lds(
      (const __attribute__((address_space(1))) void*)g,
      (__attribute__((address_space(3))) void*)l, 16, 0, 0);
}

// XCD-aware decode: bijective for total = 8 * RSX * C.
__device__ __forceinline__ void xcd_decode(int C, int RSX, int RPZ,
                                           int& z, int& rowB, int& colB) {
  int id = blockIdx.x;
  int xcd = id & 7, slot = id >> 3;
  int rs = xcd * RSX + slot / C;
  colB = (slot % C) * 128;
  z = rs / RPZ;
  rowB = (rs % RPZ) * 128;
}

// ---------------- one-shot fp32 -> (bf16 hi, bf16 lo) split, 8 elem/thread ----
__global__ __launch_bounds__(256) void cvt_kernel(
    const float* __restrict__ S0, short* __restrict__ H0, short* __restrict__ L0,
    const float* __restrict__ S1, short* __restrict__ H1, short* __restrict__ L1,
    const float* __restrict__ S2, short* __restrict__ H2, short* __restrict__ L2,
    int n0, int n1, int n2) {
  int g = blockIdx.x * 256 + threadIdx.x;
  const float* s;
  short* h;
  short* l;
  if (g < n0) {
    s = S0 + (size_t)g * 8;
    h = H0 + (size_t)g * 8;
    l = L0 + (size_t)g * 8;
  } else if (g < n0 + n1) {
    size_t t = (size_t)(g - n0);
    s = S1 + t * 8;
    h = H1 + t * 8;
    l = L1 + t * 8;
  } else {
    size_t t = (size_t)(g - n0 - n1);
    s = S2 + t * 8;
    h = H2 + t * 8;
    l = L2 + t * 8;
  }
  float4 v0 = *reinterpret_cast<const float4*>(s);
  float4 v1 = *reinterpret_cast<const float4*>(s + 4);
  float vv[8] = {v0.x, v0.y, v0.z, v0.w, v1.x, v1.y, v1.z, v1.w};
  bf16x8 th, tl;
#pragma unroll
  for (int j = 0; j < 8; ++j) {
    short hh = f2b(vv[j]);
    th[j] = hh;
    tl[j] = f2b(vv[j] - b2f(hh));
  }
  *reinterpret_cast<bf16x8*>(h) = th;
  *reinterpret_cast<bf16x8*>(l) = tl;
}

// ---------------- row sums of P (bf16, 2048 cols) -> store 1/sum ----------------
__global__ __launch_bounds__(256) void rowsum_kernel(const short* __restrict__ P,
                                                     float* __restrict__ invL) {
  int wave = threadIdx.x >> 6, lane = threadIdx.x & 63;
  size_t row = (size_t)blockIdx.x * 4 + wave;
  const short* p = P + row * 2048;
  float s = 0.f;
#pragma unroll
  for (int it = 0; it < 4; ++it) {
    bf16x8 x = *reinterpret_cast<const bf16x8*>(&p[it * 512 + lane * 8]);
#pragma unroll
    for (int j = 0; j < 8; ++j) s += b2f(x[j]);
  }
#pragma unroll
  for (int m = 32; m; m >>= 1) s += __shfl_xor(s, m);
  if (lane == 0) invL[row] = 1.0f / s;
}

// ---------------- lpsT[z][d][i] = lp[z][i][d] * invL[z*2048+i] (64x64 tiles) ----
__global__ __launch_bounds__(256) void scale_transpose_kernel(
    const short* __restrict__ lp, const float* __restrict__ invL,
    short* __restrict__ lpsT) {
  __shared__ alignas(16) short T[64 * 64];
  int id = blockIdx.x;
  int z = id / 384, r = id % 384;
  int it = r / 12, dt = r % 12;
  int i0 = it * 64, d0 = dt * 64;
  const short* src = lp + (size_t)z * 2048 * 768;
  const float* Lz = invL + (size_t)z * 2048;
  int t = threadIdx.x;
#pragma unroll
  for (int q = 0; q < 2; ++q) {
    int v = t * 2 + q;
    int ii = v >> 3, dc = (v & 7) * 8;
    float s = Lz[i0 + ii];
    bf16x8 x = *reinterpret_cast<const bf16x8*>(&src[(size_t)(i0 + ii) * 768 + d0 + dc]);
    bf16x8 y;
#pragma unroll
    for (int j = 0; j < 8; ++j) y[j] = f2b(b2f(x[j]) * s);
    *reinterpret_cast<bf16x8*>(&T[ii * 64 + (dc ^ ((ii & 7) << 3))]) = y;
  }
  __syncthreads();
  short* dst = lpsT + (size_t)z * 768 * 2048;
#pragma unroll
  for (int q = 0; q < 2; ++q) {
    int v = t * 2 + q;
    int dd = v >> 3, is = (v & 7) * 8;
    bf16x8 y;
#pragma unroll
    for (int s2 = 0; s2 < 8; ++s2) {
      int rr = is + s2;
      y[s2] = T[rr * 64 + (dd ^ ((rr & 7) << 3))];
    }
    *reinterpret_cast<bf16x8*>(&dst[(size_t)(d0 + dd) * 2048 + i0 + is]) = y;
  }
}

// ---------------- in-place per-z transpose of P (2048x2048), tile-pair swap ----
__global__ __launch_bounds__(256) void transpose_inplace_kernel(short* __restrict__ P) {
  __shared__ alignas(16) short Ta[64 * 64];
  __shared__ alignas(16) short Tb[64 * 64];
  int id = blockIdx.x;
  int z = id >> 10, r = id & 1023;
  int a = r >> 5, b = r & 31;
  if (a > b) return;
  short* Pz = P + (size_t)z * 2048 * 2048;
  int t = threadIdx.x;
#pragma unroll
  for (int q = 0; q < 2; ++q) {
    int v = t * 2 + q;
    int ii = v >> 3, cc = (v & 7) * 8;
    bf16x8 x = *reinterpret_cast<const bf16x8*>(&Pz[(size_t)(a * 64 + ii) * 2048 + b * 64 + cc]);
    *reinterpret_cast<bf16x8*>(&Ta[ii * 64 + (cc ^ ((ii & 7) << 3))]) = x;
    if (a != b) {
      bf16x8 y = *reinterpret_cast<const bf16x8*>(&Pz[(size_t)(b * 64 + ii) * 2048 + a * 64 + cc]);
      *reinterpret_cast<bf16x8*>(&Tb[ii * 64 + (cc ^ ((ii & 7) << 3))]) = y;
    }
  }
  __syncthreads();
#pragma unroll
  for (int q = 0; q < 2; ++q) {
    int v = t * 2 + q;
    int rr = v >> 3, cs = (v & 7) * 8;
    bf16x8 x, y;
#pragma unroll
    for (int s2 = 0; s2 < 8; ++s2) {
      int rs = cs + s2;
      x[s2] = Ta[rs * 64 + (rr ^ ((rs & 7) << 3))];
      if (a != b) y[s2] = Tb[rs * 64 + (rr ^ ((rs & 7) << 3))];
    }
    *reinterpret_cast<bf16x8*>(&Pz[(size_t)(b * 64 + rr) * 2048 + a * 64 + cs]) = x;
    if (a != b)
      *reinterpret_cast<bf16x8*>(&Pz[(size_t)(a * 64 + rr) * 2048 + b * 64 + cs]) = y;
  }
}

// =================================================================================
// projg: C = A @ B^T + bias, 3-pass split precision, glds w/ pre-swizzled source.
// =================================================================================
template <bool LO>
__global__ __launch_bounds__(256) void projg_kernel(
    const short* __restrict__ Ah, const short* __restrict__ Al,
    const short* __restrict__ Bh, const short* __restrict__ Bl,
    const float* __restrict__ bias,
    short* __restrict__ Ch, short* __restrict__ Cl) {
  __shared__ alignas(16) short AsH[128 * 32];
  __shared__ alignas(16) short AsL[128 * 32];
  __shared__ alignas(16) short BsH[128 * 32];
  __shared__ alignas(16) short BsL[128 * 32];
  const int tid = threadIdx.x;
  int z, rowBase, colBase;
  xcd_decode(6, 16, 128, z, rowBase, colBase);
  (void)z;
  const int lane = tid & 63;
  const int ln = lane & 15;
  const int qd = lane >> 4;
  const int w = tid >> 6;
  const int wr = w >> 1, wc = w & 1;

  f32x4 acc[4][4];
#pragma unroll
  for (int i = 0; i < 4; ++i)
#pragma unroll
    for (int j = 0; j < 4; ++j) acc[i][j] = 0.f;

  for (int kb = 0; kb < 768; kb += 32) {
#pragma unroll
    for (int q = 0; q < 2; ++q) {
      int c = q * 256 + tid;
      int r = c >> 2;
      int k0 = ((c & 3) << 3) ^ swz(r);
      size_t ao = (size_t)(rowBase + r) * 768 + kb + k0;
      size_t bo = (size_t)(colBase + r) * 768 + kb + k0;
      glds16(&Ah[ao], &AsH[c * 8]);
      glds16(&Al[ao], &AsL[c * 8]);
      glds16(&Bh[bo], &BsH[c * 8]);
      glds16(&Bl[bo], &BsL[c * 8]);
    }
    __syncthreads();
    bf16x8 ah[4], bh[4], t[4];
#pragma unroll
    for (int rt = 0; rt < 4; ++rt) {
      int m = wr * 64 + rt * 16 + ln;
      ah[rt] = *reinterpret_cast<const bf16x8*>(&AsH[m * 32 + ((qd * 8) ^ swz(m))]);
    }
#pragma unroll
    for (int ct = 0; ct < 4; ++ct) {
      int n = wc * 64 + ct * 16 + ln;
      bh[ct] = *reinterpret_cast<const bf16x8*>(&BsH[n * 32 + ((qd * 8) ^ swz(n))]);
    }
#pragma unroll
    for (int rt = 0; rt < 4; ++rt)
#pragma unroll
      for (int ct = 0; ct < 4; ++ct)
        acc[rt][ct] = __builtin_amdgcn_mfma_f32_16x16x32_bf16(ah[rt], bh[ct], acc[rt][ct], 0, 0, 0);
#pragma unroll
    for (int rt = 0; rt < 4; ++rt) {
      int m = wr * 64 + rt * 16 + ln;
      t[rt] = *reinterpret_cast<const bf16x8*>(&AsL[m * 32 + ((qd * 8) ^ swz(m))]);
    }
#pragma unroll
    for (int rt = 0; rt < 4; ++rt)
#pragma unroll
      for (int ct = 0; ct < 4; ++ct)
        acc[rt][ct] = __builtin_amdgcn_mfma_f32_16x16x32_bf16(t[rt], bh[ct], acc[rt][ct], 0, 0, 0);
#pragma unroll
    for (int ct = 0; ct < 4; ++ct) {
      int n = wc * 64 + ct * 16 + ln;
      t[ct] = *reinterpret_cast<const bf16x8*>(&BsL[n * 32 + ((qd * 8) ^ swz(n))]);
    }
#pragma unroll
    for (int rt = 0; rt < 4; ++rt)
#pragma unroll
      for (int ct = 0; ct < 4; ++ct)
        acc[rt][ct] = __builtin_amdgcn_mfma_f32_16x16x32_bf16(ah[rt], t[ct], acc[rt][ct], 0, 0, 0);
    __syncthreads();
  }

#pragma unroll
  for (int rt = 0; rt < 4; ++rt) {
    int row0 = rowBase + wr * 64 + rt * 16 + qd * 4;
#pragma unroll
    for (int ct = 0; ct < 4; ++ct) {
      int col = colBase + wc * 64 + ct * 16 + ln;
      float bb = bias[col];
      f32x4 a = acc[rt][ct];
#pragma unroll
      for (int r = 0; r < 4; ++r) {
        float val = a[r] + bb;
        short h = f2b(val);
        Ch[(size_t)(row0 + r) * 768 + col] = h;
        if constexpr (LO) Cl[(size_t)(row0 + r) * 768 + col] = f2b(val - b2f(h));
      }
    }
  }
}

// =================================================================================
// sim2: P = exp(vp_hi*(lp_hi+lp_lo)^T - 20), glds staging w/ pre-swizzled source.
// =================================================================================
__global__ __launch_bounds__(256) void sim2_kernel(const short* __restrict__ vp,
                                                   const short* __restrict__ lph,
                                                   const short* __restrict__ lpl,
                                                   short* __restrict__ P) {
  __shared__ alignas(16) short As[128 * 32];
  __shared__ alignas(16) short Bh[128 * 32];
  __shared__ alignas(16) short Bl[128 * 32];
  const int tid = threadIdx.x;
  int z, rowBase, colBase;
  xcd_decode(16, 16, 16, z, rowBase, colBase);
  const short* Az = vp + (size_t)z * 2048 * 768;
  const short* B0 = lph + (size_t)z * 2048 * 768;
  const short* B1 = lpl + (size_t)z * 2048 * 768;
  const int lane = tid & 63;
  const int ln = lane & 15;
  const int qd = lane >> 4;
  const int w = tid >> 6;
  const int wr = w >> 1, wc = w & 1;

  f32x4 acc[4][4];
#pragma unroll
  for (int i = 0; i < 4; ++i)
#pragma unroll
    for (int j = 0; j < 4; ++j) acc[i][j] = 0.f;

  for (int kb = 0; kb < 768; kb += 32) {
#pragma unroll
    for (int q = 0; q < 2; ++q) {
      int c = q * 256 + tid;
      int r = c >> 2;
      int k0 = ((c & 3) << 3) ^ swz(r);
      glds16(&Az[(size_t)(rowBase + r) * 768 + kb + k0], &As[c * 8]);
      glds16(&B0[(size_t)(colBase + r) * 768 + kb + k0], &Bh[c * 8]);
      glds16(&B1[(size_t)(colBase + r) * 768 + kb + k0], &Bl[c * 8]);
    }
    __syncthreads();
    bf16x8 af[4], bf[4];
#pragma unroll
    for (int rt = 0; rt < 4; ++rt) {
      int m = wr * 64 + rt * 16 + ln;
      af[rt] = *reinterpret_cast<const bf16x8*>(&As[m * 32 + ((qd * 8) ^ swz(m))]);
    }
#pragma unroll
    for (int ct = 0; ct < 4; ++ct) {
      int n = wc * 64 + ct * 16 + ln;
      bf[ct] = *reinterpret_cast<const bf16x8*>(&Bh[n * 32 + ((qd * 8) ^ swz(n))]);
    }
#pragma unroll
    for (int rt = 0; rt < 4; ++rt)
#pragma unroll
      for (int ct = 0; ct < 4; ++ct)
        acc[rt][ct] = __builtin_amdgcn_mfma_f32_16x16x32_bf16(af[rt], bf[ct], acc[rt][ct], 0, 0, 0);
#pragma unroll
    for (int ct = 0; ct < 4; ++ct) {
      int n = wc * 64 + ct * 16 + ln;
      bf[ct] = *reinterpret_cast<const bf16x8*>(&Bl[n * 32 + ((qd * 8) ^ swz(n))]);
    }
#pragma unroll
    for (int rt = 0; rt < 4; ++rt)
#pragma unroll
      for (int ct = 0; ct < 4; ++ct)
        acc[rt][ct] = __builtin_amdgcn_mfma_f32_16x16x32_bf16(af[rt], bf[ct], acc[rt][ct], 0, 0, 0);
    __syncthreads();
  }

  short* Pz = P + (size_t)z * 2048 * 2048;
#pragma unroll
  for (int rt = 0; rt < 4; ++rt) {
    int row0 = rowBase + wr * 64 + rt * 16 + qd * 4;
#pragma unroll
    for (int ct = 0; ct < 4; ++ct) {
      int col = colBase + wc * 64 + ct * 16 + ln;
      f32x4 a = acc[rt][ct];
#pragma unroll
      for (int r = 0; r < 4; ++r)
        Pz[(size_t)(row0 + r) * 2048 + col] = f2b(__expf(a[r] - 20.0f));
    }
  }
}

// =================================================================================
// gemm_k: C[m,n] = sum_k A[m,k]*B[n,k], bf16. Plain operands via glds
// (pre-swizzled source). TB: B given as [K,N] -> register-transpose staging.
// SB: scale B by invL[k]. DUALA: A split 768|768.
// MODE 2: bf16 = acc*invL[row]; MODE 3: bf16 = acc; MODE 4: fp32 = acc+bias[col]
// =================================================================================
template <int MODE, bool TB, bool SB, bool DUALA>
__global__ __launch_bounds__(256) void gemm_k(const short* __restrict__ A,
                                              const short* __restrict__ A2,
                                              const void* __restrict__ B,
                                              void* __restrict__ C,
                                              const float* __restrict__ bias,
                                              const float* __restrict__ invL,
                                              int C_, int RSX_, int RPZ_,
                                              int K, int ldA, int ldB, int ldC,
                                              long sA, long sB, long sC, long sL) {
  __shared__ alignas(16) short As[128 * 32];
  __shared__ alignas(16) short Bs[128 * 32];
  const int tid = threadIdx.x;
  int z, rowBase, colBase;
  xcd_decode(C_, RSX_, RPZ_, z, rowBase, colBase);
  const short* Az = A + (size_t)z * sA;
  const float* Lz = invL ? (invL + (size_t)z * sL) : nullptr;
  const int lane = tid & 63;
  const int ln = lane & 15;
  const int qd = lane >> 4;
  const int w = tid >> 6;
  const int wr = w >> 1, wc = w & 1;

  f32x4 acc[4][4];
#pragma unroll
  for (int i = 0; i < 4; ++i)
#pragma unroll
    for (int j = 0; j < 4; ++j) acc[i][j] = 0.f;

  for (int kb = 0; kb < K; kb += 32) {
#pragma unroll
    for (int q = 0; q < 2; ++q) {
      int c = q * 256 + tid;
      int r = c >> 2;
      int k0 = ((c & 3) << 3) ^ swz(r);
      int kk = kb + k0;
      const short* src;
      if constexpr (DUALA) {
        src = (kk < 768) ? &Az[(size_t)(rowBase + r) * 768 + kk]
                         : &A2[(size_t)(rowBase + r) * 768 + kk - 768];
      } else {
        src = &Az[(size_t)(rowBase + r) * ldA + kk];
      }
      glds16(src, &As[c * 8]);
    }
    if constexpr (TB) {
      const short* Bz = (const short*)B + (size_t)z * sB;
#pragma unroll
      for (int q = 0; q < 2; ++q) {
        int task = q * 256 + tid;
        int n = task & 127;
        int kc = (task >> 7) << 3;
        bf16x8 t;
#pragma unroll
        for (int s = 0; s < 8; ++s) {
          short v = Bz[(size_t)(kb + kc + s) * ldB + colBase + n];
          if constexpr (SB) v = f2b(b2f(v) * Lz[kb + kc + s]);
          t[s] = v;
        }
        *reinterpret_cast<bf16x8*>(&Bs[n * 32 + (kc ^ swz(n))]) = t;
      }
    } else {
      const short* Bz = (const short*)B + (size_t)z * sB;
#pragma unroll
      for (int q = 0; q < 2; ++q) {
        int c = q * 256 + tid;
        int r = c >> 2;
        int k0 = ((c & 3) << 3) ^ swz(r);
        glds16(&Bz[(size_t)(colBase + r) * ldB + kb + k0], &Bs[c * 8]);
      }
    }
    __syncthreads();
    bf16x8 af[4], bfv[4];
#pragma unroll
    for (int rt = 0; rt < 4; ++rt) {
      int m = wr * 64 + rt * 16 + ln;
      af[rt] = *reinterpret_cast<const bf16x8*>(&As[m * 32 + ((qd * 8) ^ swz(m))]);
    }
#pragma unroll
    for (int ct = 0; ct < 4; ++ct) {
      int n = wc * 64 + ct * 16 + ln;
      bfv[ct] = *reinterpret_cast<const bf16x8*>(&Bs[n * 32 + ((qd * 8) ^ swz(n))]);
    }
#pragma unroll
    for (int rt = 0; rt < 4; ++rt)
#pragma unroll
      for (int ct = 0; ct < 4; ++ct)
        acc[rt][ct] =
            __builtin_amdgcn_mfma_f32_16x16x32_bf16(af[rt], bfv[ct], acc[rt][ct], 0, 0, 0);
    __syncthreads();
  }

#pragma unroll
  for (int rt = 0; rt < 4; ++rt) {
    int row0 = rowBase + wr * 64 + rt * 16 + qd * 4;
#pragma unroll
    for (int ct = 0; ct < 4; ++ct) {
      int col = colBase + wc * 64 + ct * 16 + ln;
      f32x4 a = acc[rt][ct];
      if constexpr (MODE == 2) {
        short* Co = (short*)C + (size_t)z * sC;
#pragma unroll
        for (int r = 0; r < 4; ++r)
          Co[(size_t)(row0 + r) * ldC + col] = f2b(a[r] * Lz[row0 + r]);
      } else if constexpr (MODE == 3) {
        short* Co = (short*)C + (size_t)z * sC;
#pragma unroll
        for (int r = 0; r < 4; ++r) Co[(size_t)(row0 + r) * ldC + col] = f2b(a[r]);
      } else {  // MODE 4
        float* Co = (float*)C + (size_t)z * sC;
        float bb = bias[col];
#pragma unroll
        for (int r = 0; r < 4; ++r) Co[(size_t)(row0 + r) * ldC + col] = a[r] + bb;
      }
    }
  }
}

extern "C" void kernel_launch(void* const* d_in, const int* in_sizes, int n_in,
                              void* d_out, int out_size, void* d_ws, size_t ws_size,
                              hipStream_t stream) {
  const float* vf = (const float*)d_in[0];
  const float* lf = (const float*)d_in[1];
  const float* Wv = (const float*)d_in[2];
  const float* bv = (const float*)d_in[3];
  const float* Wl = (const float*)d_in[4];
  const float* bl = (const float*)d_in[5];
  const float* Wo = (const float*)d_in[6];
  const float* bo = (const float*)d_in[7];

  constexpr int Bz = 8, L = 2048, D = 768, M = Bz * L, D2 = 2 * D;
  constexpr size_t PLANE = (size_t)M * D;      // 12,582,912 elems
  constexpr size_t WPLANE = (size_t)D * D;     // 589,824 elems

  char* wp = (char*)d_ws;
  auto alloc = [&](size_t bytes) {
    char* p = wp;
    wp += (bytes + 255) & ~(size_t)255;
    return p;
  };
  short* vp_hi = (short*)alloc(PLANE * 2);               // 25.2 MB; -> al after step4
  short* P     = (short*)alloc((size_t)Bz * L * L * 2);  // 67.1 MB; -> PT -> out_tmp
  float* invL  = (float*)alloc((size_t)M * 4);           // 64 KB

  // direct mode: lp planes in ws, step-6 writes fp32 straight to d_out.
  size_t need_direct = (size_t)(wp - (char*)d_ws) + 2 * PLANE * 2 + 512;
  bool direct = ws_size >= need_direct;

  short *lp_hi, *lp_lo;
  if (direct) {
    lp_hi = (short*)alloc(PLANE * 2);
    lp_lo = (short*)alloc(PLANE * 2);
  } else {
    lp_hi = (short*)d_out;
    lp_lo = lp_hi + PLANE;
  }
  short* lpsT = lp_lo;   // lp_lo dead after sim2
  short* av   = lp_hi;   // lp_hi dead after scale_transpose
  short* al   = vp_hi;   // vp_hi dead after step 4
  // Wo bf16 planes live in the P region tail AFTER step 5 (PT dead):
  // out_tmp occupies [0, 50.33 MB); woh/wol at [50.33, 55.05 MB) of the 67.1 MB.
  short* woh = P + 2 * PLANE;
  short* wol = woh + (size_t)D * D2;
  float* out_tmp = direct ? (float*)d_out : (float*)P;

  // Transient hi/lo planes inside the (not-yet-written) P region (55.0 <= 67.1 MB)
  short* fh  = P;
  short* fl  = P + PLANE;
  short* wvh = P + 2 * PLANE;
  short* wvl = wvh + WPLANE;
  short* wlh = wvl + WPLANE;
  short* wll = wlh + WPLANE;

  constexpr int GF  = (int)(PLANE / 8);        // 1,572,864 groups (feature)
  constexpr int GW  = (int)(WPLANE / 8);       // 73,728 groups (proj weight)
  constexpr int GWO = (int)((size_t)D * D2 / 8);  // 147,456 groups (Wo)

  // 1a) convert vision features + both proj weights
  cvt_kernel<<<dim3((GF + 2 * GW) / 256), 256, 0, stream>>>(
      vf, fh, fl, Wv, wvh, wvl, Wl, wlh, wll, GF, GW, GW);

  // 1b) vision projection -> vp_hi
  projg_kernel<false><<<dim3(768), 256, 0, stream>>>(fh, fl, wvh, wvl, bv, vp_hi, nullptr);

  // 1c) convert language features
  cvt_kernel<<<dim3(GF / 256), 256, 0, stream>>>(
      lf, fh, fl, nullptr, nullptr, nullptr, nullptr, nullptr, nullptr, GF, 0, 0);

  // 1d) language projection -> lp_hi + lp_lo
  projg_kernel<true><<<dim3(768), 256, 0, stream>>>(fh, fl, wlh, wll, bl, lp_hi, lp_lo);

  // 2) P = exp(vp*lp^T - 20). 2048 blocks
  sim2_kernel<<<dim3(2048), 256, 0, stream>>>(vp_hi, lp_hi, lp_lo, P);

  // 3) invL = 1/rowsum(P)
  rowsum_kernel<<<dim3(M / 4), 256, 0, stream>>>(P, invL);

  // 4) lpsT[z][d][i] = lp[z][i][d] * invL  (lp_lo slot; lp_hi freed after)
  scale_transpose_kernel<<<dim3(3072), 256, 0, stream>>>(lp_hi, invL, lpsT);

  // 5) aligned_vision = (P @ vp) * invL[row] -> av (lp_hi slot). B=vp^T staged.
  gemm_k<2, true, false, false><<<dim3(768), 256, 0, stream>>>(
      P, nullptr, vp_hi, av, nullptr, invL, 6, 16, 16, L, L, D, D,
      (long)L * L, (long)L * D, (long)L * D, (long)L);

  // 6) P -> P^T in place (per z, 64x64 tile-pair swap). 8192 blocks
  transpose_inplace_kernel<<<dim3(8192), 256, 0, stream>>>(P);

  // 7) aligned_language = P^T @ lps -> al (vp_hi slot). Both operands plain glds.
  gemm_k<3, false, false, false><<<dim3(768), 256, 0, stream>>>(
      P, nullptr, lpsT, al, nullptr, nullptr, 6, 16, 16, L, L, L, D,
      (long)L * L, (long)D * L, (long)L * D, (long)L);

  // 8) convert Wo -> bf16 (P region tail; PT dead now)
  cvt_kernel<<<dim3(GWO / 256), 256, 0, stream>>>(
      Wo, woh, wol, nullptr, nullptr, nullptr, nullptr, nullptr, nullptr, GWO, 0, 0);

  // 9) out = [av | al] @ Wo^T + bo (fp32). B = woh plain bf16 glds.
  gemm_k<4, false, false, true><<<dim3(768), 256, 0, stream>>>(
      av, al, woh, out_tmp, bo, nullptr, 6, 16, 128, D2, D, D2, D, 0, 0, 0, 0);

  // 10) out_tmp -> d_out (only when step 9 couldn't write directly)
  if (!direct)
    hipMemcpyAsync(d_out, out_tmp, (size_t)M * D * 4, hipMemcpyDeviceToDevice, stream);
}

// Round 5
// 643.577 us; speedup vs baseline: 1.0861x; 1.0223x over previous
//
#include <hip/hip_runtime.h>
#include <stdint.h>

typedef __attribute__((ext_vector_type(8))) short bf16x8;
typedef __attribute__((ext_vector_type(8))) _Float16 f16x8;
typedef __attribute__((ext_vector_type(4))) float f32x4;

__device__ __forceinline__ float b2f(short h) {
  return __uint_as_float(((unsigned)(unsigned short)h) << 16);
}
__device__ __forceinline__ short f2b(float f) {
  unsigned u = __float_as_uint(f);
  u += 0x7fffu + ((u >> 16) & 1u);
  return (short)(u >> 16);
}
__device__ __forceinline__ short f2h(float f) {
  _Float16 h = (_Float16)f;
  return __builtin_bit_cast(short, h);
}
__device__ __forceinline__ float h2f(short s) {
  return (float)__builtin_bit_cast(_Float16, s);
}

// chunk-swizzle (in shorts): XOR the 8-short chunk index with (r>>1)&3.
__device__ __forceinline__ int swz(int r) { return (r & 6) << 2; }

// async global->LDS, 16 B per lane (global_load_lds_dwordx4)
__device__ __forceinline__ void glds16(const void* g, void* l) {
  __builtin_amdgcn_global_load_lds(
      (const __attribute__((address_space(1))) void*)g,
      (__attribute__((address_space(3))) void*)l, 16, 0, 0);
}

// XCD-aware decode: bijective for total = 8 * RSX * C.
__device__ __forceinline__ void xcd_decode(int C, int RSX, int RPZ,
                                           int& z, int& rowB, int& colB) {
  int id = blockIdx.x;
  int xcd = id & 7, slot = id >> 3;
  int rs = xcd * RSX + slot / C;
  colB = (slot % C) * 128;
  z = rs / RPZ;
  rowB = (rs % RPZ) * 128;
}

// ---------------- one-shot fp32 -> (bf16 hi, bf16 lo) split, 8 elem/thread ----
__global__ __launch_bounds__(256) void cvt_kernel(
    const float* __restrict__ S0, short* __restrict__ H0, short* __restrict__ L0,
    const float* __restrict__ S1, short* __restrict__ H1, short* __restrict__ L1,
    const float* __restrict__ S2, short* __restrict__ H2, short* __restrict__ L2,
    int n0, int n1, int n2) {
  int g = blockIdx.x * 256 + threadIdx.x;
  const float* s;
  short* h;
  short* l;
  if (g < n0) {
    s = S0 + (size_t)g * 8;
    h = H0 + (size_t)g * 8;
    l = L0 + (size_t)g * 8;
  } else if (g < n0 + n1) {
    size_t t = (size_t)(g - n0);
    s = S1 + t * 8;
    h = H1 + t * 8;
    l = L1 + t * 8;
  } else {
    size_t t = (size_t)(g - n0 - n1);
    s = S2 + t * 8;
    h = H2 + t * 8;
    l = L2 + t * 8;
  }
  float4 v0 = *reinterpret_cast<const float4*>(s);
  float4 v1 = *reinterpret_cast<const float4*>(s + 4);
  float vv[8] = {v0.x, v0.y, v0.z, v0.w, v1.x, v1.y, v1.z, v1.w};
  bf16x8 th, tl;
#pragma unroll
  for (int j = 0; j < 8; ++j) {
    short hh = f2b(vv[j]);
    th[j] = hh;
    tl[j] = f2b(vv[j] - b2f(hh));
  }
  *reinterpret_cast<bf16x8*>(h) = th;
  *reinterpret_cast<bf16x8*>(l) = tl;
}

// ---------------- zero / reciprocal helpers ----------------
__global__ __launch_bounds__(256) void zero_kernel(float* __restrict__ p, int n) {
  int i = blockIdx.x * 256 + threadIdx.x;
  if (i < n) p[i] = 0.f;
}
__global__ __launch_bounds__(256) void recip_kernel(const float* __restrict__ s,
                                                    float* __restrict__ invL, int n) {
  int i = blockIdx.x * 256 + threadIdx.x;
  if (i < n) invL[i] = 1.0f / s[i];
}

// ---------------- lpsT[z][d][i] = lp[z][i][d] * invL[z*2048+i] (64x64 tiles) ----
__global__ __launch_bounds__(256) void scale_transpose_kernel(
    const short* __restrict__ lp, const float* __restrict__ invL,
    short* __restrict__ lpsT) {
  __shared__ alignas(16) short T[64 * 64];
  int id = blockIdx.x;
  int z = id / 384, r = id % 384;
  int it = r / 12, dt = r % 12;
  int i0 = it * 64, d0 = dt * 64;
  const short* src = lp + (size_t)z * 2048 * 768;
  const float* Lz = invL + (size_t)z * 2048;
  int t = threadIdx.x;
#pragma unroll
  for (int q = 0; q < 2; ++q) {
    int v = t * 2 + q;
    int ii = v >> 3, dc = (v & 7) * 8;
    float s = Lz[i0 + ii];
    bf16x8 x = *reinterpret_cast<const bf16x8*>(&src[(size_t)(i0 + ii) * 768 + d0 + dc]);
    bf16x8 y;
#pragma unroll
    for (int j = 0; j < 8; ++j) y[j] = f2b(b2f(x[j]) * s);
    *reinterpret_cast<bf16x8*>(&T[ii * 64 + (dc ^ ((ii & 7) << 3))]) = y;
  }
  __syncthreads();
  short* dst = lpsT + (size_t)z * 768 * 2048;
#pragma unroll
  for (int q = 0; q < 2; ++q) {
    int v = t * 2 + q;
    int dd = v >> 3, is = (v & 7) * 8;
    bf16x8 y;
#pragma unroll
    for (int s2 = 0; s2 < 8; ++s2) {
      int rr = is + s2;
      y[s2] = T[rr * 64 + (dd ^ ((rr & 7) << 3))];
    }
    *reinterpret_cast<bf16x8*>(&dst[(size_t)(d0 + dd) * 2048 + i0 + is]) = y;
  }
}

// ---------------- in-place per-z transpose of P (2048x2048), tile-pair swap ----
__global__ __launch_bounds__(256) void transpose_inplace_kernel(short* __restrict__ P) {
  __shared__ alignas(16) short Ta[64 * 64];
  __shared__ alignas(16) short Tb[64 * 64];
  int id = blockIdx.x;
  int z = id >> 10, r = id & 1023;
  int a = r >> 5, b = r & 31;
  if (a > b) return;
  short* Pz = P + (size_t)z * 2048 * 2048;
  int t = threadIdx.x;
#pragma unroll
  for (int q = 0; q < 2; ++q) {
    int v = t * 2 + q;
    int ii = v >> 3, cc = (v & 7) * 8;
    bf16x8 x = *reinterpret_cast<const bf16x8*>(&Pz[(size_t)(a * 64 + ii) * 2048 + b * 64 + cc]);
    *reinterpret_cast<bf16x8*>(&Ta[ii * 64 + (cc ^ ((ii & 7) << 3))]) = x;
    if (a != b) {
      bf16x8 y = *reinterpret_cast<const bf16x8*>(&Pz[(size_t)(b * 64 + ii) * 2048 + a * 64 + cc]);
      *reinterpret_cast<bf16x8*>(&Tb[ii * 64 + (cc ^ ((ii & 7) << 3))]) = y;
    }
  }
  __syncthreads();
#pragma unroll
  for (int q = 0; q < 2; ++q) {
    int v = t * 2 + q;
    int rr = v >> 3, cs = (v & 7) * 8;
    bf16x8 x, y;
#pragma unroll
    for (int s2 = 0; s2 < 8; ++s2) {
      int rs = cs + s2;
      x[s2] = Ta[rs * 64 + (rr ^ ((rs & 7) << 3))];
      if (a != b) y[s2] = Tb[rs * 64 + (rr ^ ((rs & 7) << 3))];
    }
    *reinterpret_cast<bf16x8*>(&Pz[(size_t)(b * 64 + rr) * 2048 + a * 64 + cs]) = x;
    if (a != b)
      *reinterpret_cast<bf16x8*>(&Pz[(size_t)(a * 64 + rr) * 2048 + b * 64 + cs]) = y;
  }
}

// =================================================================================
// projg: C = A @ B^T + bias, 3-pass split precision, glds w/ pre-swizzled source.
// OM=0: write f16 plane only (Ch). OM=1: write bf16 plane (Ch) + f16 plane (Cl).
// =================================================================================
template <int OM>
__global__ __launch_bounds__(256) void projg_kernel(
    const short* __restrict__ Ah, const short* __restrict__ Al,
    const short* __restrict__ Bh, const short* __restrict__ Bl,
    const float* __restrict__ bias,
    short* __restrict__ Ch, short* __restrict__ Cl) {
  __shared__ alignas(16) short AsH[128 * 32];
  __shared__ alignas(16) short AsL[128 * 32];
  __shared__ alignas(16) short BsH[128 * 32];
  __shared__ alignas(16) short BsL[128 * 32];
  const int tid = threadIdx.x;
  int z, rowBase, colBase;
  xcd_decode(6, 16, 128, z, rowBase, colBase);
  (void)z;
  const int lane = tid & 63;
  const int ln = lane & 15;
  const int qd = lane >> 4;
  const int w = tid >> 6;
  const int wr = w >> 1, wc = w & 1;

  f32x4 acc[4][4];
#pragma unroll
  for (int i = 0; i < 4; ++i)
#pragma unroll
    for (int j = 0; j < 4; ++j) acc[i][j] = 0.f;

  for (int kb = 0; kb < 768; kb += 32) {
#pragma unroll
    for (int q = 0; q < 2; ++q) {
      int c = q * 256 + tid;
      int r = c >> 2;
      int k0 = ((c & 3) << 3) ^ swz(r);
      size_t ao = (size_t)(rowBase + r) * 768 + kb + k0;
      size_t bo = (size_t)(colBase + r) * 768 + kb + k0;
      glds16(&Ah[ao], &AsH[c * 8]);
      glds16(&Al[ao], &AsL[c * 8]);
      glds16(&Bh[bo], &BsH[c * 8]);
      glds16(&Bl[bo], &BsL[c * 8]);
    }
    __syncthreads();
    bf16x8 ah[4], bh[4], t[4];
#pragma unroll
    for (int rt = 0; rt < 4; ++rt) {
      int m = wr * 64 + rt * 16 + ln;
      ah[rt] = *reinterpret_cast<const bf16x8*>(&AsH[m * 32 + ((qd * 8) ^ swz(m))]);
    }
#pragma unroll
    for (int ct = 0; ct < 4; ++ct) {
      int n = wc * 64 + ct * 16 + ln;
      bh[ct] = *reinterpret_cast<const bf16x8*>(&BsH[n * 32 + ((qd * 8) ^ swz(n))]);
    }
#pragma unroll
    for (int rt = 0; rt < 4; ++rt)
#pragma unroll
      for (int ct = 0; ct < 4; ++ct)
        acc[rt][ct] = __builtin_amdgcn_mfma_f32_16x16x32_bf16(ah[rt], bh[ct], acc[rt][ct], 0, 0, 0);
#pragma unroll
    for (int rt = 0; rt < 4; ++rt) {
      int m = wr * 64 + rt * 16 + ln;
      t[rt] = *reinterpret_cast<const bf16x8*>(&AsL[m * 32 + ((qd * 8) ^ swz(m))]);
    }
#pragma unroll
    for (int rt = 0; rt < 4; ++rt)
#pragma unroll
      for (int ct = 0; ct < 4; ++ct)
        acc[rt][ct] = __builtin_amdgcn_mfma_f32_16x16x32_bf16(t[rt], bh[ct], acc[rt][ct], 0, 0, 0);
#pragma unroll
    for (int ct = 0; ct < 4; ++ct) {
      int n = wc * 64 + ct * 16 + ln;
      t[ct] = *reinterpret_cast<const bf16x8*>(&BsL[n * 32 + ((qd * 8) ^ swz(n))]);
    }
#pragma unroll
    for (int rt = 0; rt < 4; ++rt)
#pragma unroll
      for (int ct = 0; ct < 4; ++ct)
        acc[rt][ct] = __builtin_amdgcn_mfma_f32_16x16x32_bf16(ah[rt], t[ct], acc[rt][ct], 0, 0, 0);
    __syncthreads();
  }

#pragma unroll
  for (int rt = 0; rt < 4; ++rt) {
    int row0 = rowBase + wr * 64 + rt * 16 + qd * 4;
#pragma unroll
    for (int ct = 0; ct < 4; ++ct) {
      int col = colBase + wc * 64 + ct * 16 + ln;
      float bb = bias[col];
      f32x4 a = acc[rt][ct];
#pragma unroll
      for (int r = 0; r < 4; ++r) {
        float val = a[r] + bb;
        if constexpr (OM == 0) {
          Ch[(size_t)(row0 + r) * 768 + col] = f2h(val);
        } else {
          Ch[(size_t)(row0 + r) * 768 + col] = f2b(val);
          Cl[(size_t)(row0 + r) * 768 + col] = f2h(val);
        }
      }
    }
  }
}

// =================================================================================
// sim2: P = exp(vp16*lp16^T - 20), single fp16 MFMA pass, glds staging w/
// pre-swizzled source. Epilogue: fused bf16-rounded row sums -> atomicAdd(S).
// =================================================================================
__global__ __launch_bounds__(256) void sim2_kernel(const short* __restrict__ vp,
                                                   const short* __restrict__ lp,
                                                   short* __restrict__ P,
                                                   float* __restrict__ S) {
  __shared__ alignas(16) short As[128 * 32];
  __shared__ alignas(16) short Bs[128 * 32];
  const int tid = threadIdx.x;
  int z, rowBase, colBase;
  xcd_decode(16, 16, 16, z, rowBase, colBase);
  const short* Az = vp + (size_t)z * 2048 * 768;
  const short* Bz = lp + (size_t)z * 2048 * 768;
  const int lane = tid & 63;
  const int ln = lane & 15;
  const int qd = lane >> 4;
  const int w = tid >> 6;
  const int wr = w >> 1, wc = w & 1;

  f32x4 acc[4][4];
#pragma unroll
  for (int i = 0; i < 4; ++i)
#pragma unroll
    for (int j = 0; j < 4; ++j) acc[i][j] = 0.f;

  for (int kb = 0; kb < 768; kb += 32) {
#pragma unroll
    for (int q = 0; q < 2; ++q) {
      int c = q * 256 + tid;
      int r = c >> 2;
      int k0 = ((c & 3) << 3) ^ swz(r);
      glds16(&Az[(size_t)(rowBase + r) * 768 + kb + k0], &As[c * 8]);
      glds16(&Bz[(size_t)(colBase + r) * 768 + kb + k0], &Bs[c * 8]);
    }
    __syncthreads();
    f16x8 af[4], bf[4];
#pragma unroll
    for (int rt = 0; rt < 4; ++rt) {
      int m = wr * 64 + rt * 16 + ln;
      af[rt] = *reinterpret_cast<const f16x8*>(&As[m * 32 + ((qd * 8) ^ swz(m))]);
    }
#pragma unroll
    for (int ct = 0; ct < 4; ++ct) {
      int n = wc * 64 + ct * 16 + ln;
      bf[ct] = *reinterpret_cast<const f16x8*>(&Bs[n * 32 + ((qd * 8) ^ swz(n))]);
    }
#pragma unroll
    for (int rt = 0; rt < 4; ++rt)
#pragma unroll
      for (int ct = 0; ct < 4; ++ct)
        acc[rt][ct] = __builtin_amdgcn_mfma_f32_16x16x32_f16(af[rt], bf[ct], acc[rt][ct], 0, 0, 0);
    __syncthreads();
  }

  short* Pz = P + (size_t)z * 2048 * 2048;
  float* Sz = S + (size_t)z * 2048;
#pragma unroll
  for (int rt = 0; rt < 4; ++rt) {
    int row0 = rowBase + wr * 64 + rt * 16 + qd * 4;
    float rowp[4] = {0.f, 0.f, 0.f, 0.f};
#pragma unroll
    for (int ct = 0; ct < 4; ++ct) {
      int col = colBase + wc * 64 + ct * 16 + ln;
      f32x4 a = acc[rt][ct];
#pragma unroll
      for (int r = 0; r < 4; ++r) {
        short h = f2b(__expf(a[r] - 20.0f));
        Pz[(size_t)(row0 + r) * 2048 + col] = h;
        rowp[r] += b2f(h);
      }
    }
#pragma unroll
    for (int r = 0; r < 4; ++r) {
      float v = rowp[r];
      v += __shfl_xor(v, 1);
      v += __shfl_xor(v, 2);
      v += __shfl_xor(v, 4);
      v += __shfl_xor(v, 8);
      if (ln == 0) atomicAdd(&Sz[row0 + r], v);
    }
  }
}

// =================================================================================
// gemm_k: C[m,n] = sum_k A[m,k]*B[n,k], bf16. Plain operands via glds
// (pre-swizzled source). TB: B given as [K,N] -> register-transpose staging.
// SB: scale B by invL[k]. F16B: B stored fp16, convert to bf16 in staging.
// DUALA: A split 768|768.
// MODE 2: bf16 = acc*invL[row]; MODE 3: bf16 = acc; MODE 4: fp32 = acc+bias[col]
// =================================================================================
template <int MODE, bool TB, bool SB, bool F16B, bool DUALA>
__global__ __launch_bounds__(256) void gemm_k(const short* __restrict__ A,
                                              const short* __restrict__ A2,
                                              const void* __restrict__ B,
                                              void* __restrict__ C,
                                              const float* __restrict__ bias,
                                              const float* __restrict__ invL,
                                              int C_, int RSX_, int RPZ_,
                                              int K, int ldA, int ldB, int ldC,
                                              long sA, long sB, long sC, long sL) {
  __shared__ alignas(16) short As[128 * 32];
  __shared__ alignas(16) short Bs[128 * 32];
  const int tid = threadIdx.x;
  int z, rowBase, colBase;
  xcd_decode(C_, RSX_, RPZ_, z, rowBase, colBase);
  const short* Az = A + (size_t)z * sA;
  const float* Lz = invL ? (invL + (size_t)z * sL) : nullptr;
  const int lane = tid & 63;
  const int ln = lane & 15;
  const int qd = lane >> 4;
  const int w = tid >> 6;
  const int wr = w >> 1, wc = w & 1;

  f32x4 acc[4][4];
#pragma unroll
  for (int i = 0; i < 4; ++i)
#pragma unroll
    for (int j = 0; j < 4; ++j) acc[i][j] = 0.f;

  for (int kb = 0; kb < K; kb += 32) {
#pragma unroll
    for (int q = 0; q < 2; ++q) {
      int c = q * 256 + tid;
      int r = c >> 2;
      int k0 = ((c & 3) << 3) ^ swz(r);
      int kk = kb + k0;
      const short* src;
      if constexpr (DUALA) {
        src = (kk < 768) ? &Az[(size_t)(rowBase + r) * 768 + kk]
                         : &A2[(size_t)(rowBase + r) * 768 + kk - 768];
      } else {
        src = &Az[(size_t)(rowBase + r) * ldA + kk];
      }
      glds16(src, &As[c * 8]);
    }
    if constexpr (TB) {
      const short* Bz = (const short*)B + (size_t)z * sB;
#pragma unroll
      for (int q = 0; q < 2; ++q) {
        int task = q * 256 + tid;
        int n = task & 127;
        int kc = (task >> 7) << 3;
        bf16x8 t;
#pragma unroll
        for (int s = 0; s < 8; ++s) {
          short v = Bz[(size_t)(kb + kc + s) * ldB + colBase + n];
          if constexpr (F16B) v = f2b(h2f(v));
          if constexpr (SB) v = f2b(b2f(v) * Lz[kb + kc + s]);
          t[s] = v;
        }
        *reinterpret_cast<bf16x8*>(&Bs[n * 32 + (kc ^ swz(n))]) = t;
      }
    } else {
      const short* Bz = (const short*)B + (size_t)z * sB;
#pragma unroll
      for (int q = 0; q < 2; ++q) {
        int c = q * 256 + tid;
        int r = c >> 2;
        int k0 = ((c & 3) << 3) ^ swz(r);
        glds16(&Bz[(size_t)(colBase + r) * ldB + kb + k0], &Bs[c * 8]);
      }
    }
    __syncthreads();
    bf16x8 af[4], bfv[4];
#pragma unroll
    for (int rt = 0; rt < 4; ++rt) {
      int m = wr * 64 + rt * 16 + ln;
      af[rt] = *reinterpret_cast<const bf16x8*>(&As[m * 32 + ((qd * 8) ^ swz(m))]);
    }
#pragma unroll
    for (int ct = 0; ct < 4; ++ct) {
      int n = wc * 64 + ct * 16 + ln;
      bfv[ct] = *reinterpret_cast<const bf16x8*>(&Bs[n * 32 + ((qd * 8) ^ swz(n))]);
    }
#pragma unroll
    for (int rt = 0; rt < 4; ++rt)
#pragma unroll
      for (int ct = 0; ct < 4; ++ct)
        acc[rt][ct] =
            __builtin_amdgcn_mfma_f32_16x16x32_bf16(af[rt], bfv[ct], acc[rt][ct], 0, 0, 0);
    __syncthreads();
  }

#pragma unroll
  for (int rt = 0; rt < 4; ++rt) {
    int row0 = rowBase + wr * 64 + rt * 16 + qd * 4;
#pragma unroll
    for (int ct = 0; ct < 4; ++ct) {
      int col = colBase + wc * 64 + ct * 16 + ln;
      f32x4 a = acc[rt][ct];
      if constexpr (MODE == 2) {
        short* Co = (short*)C + (size_t)z * sC;
#pragma unroll
        for (int r = 0; r < 4; ++r)
          Co[(size_t)(row0 + r) * ldC + col] = f2b(a[r] * Lz[row0 + r]);
      } else if constexpr (MODE == 3) {
        short* Co = (short*)C + (size_t)z * sC;
#pragma unroll
        for (int r = 0; r < 4; ++r) Co[(size_t)(row0 + r) * ldC + col] = f2b(a[r]);
      } else {  // MODE 4
        float* Co = (float*)C + (size_t)z * sC;
        float bb = bias[col];
#pragma unroll
        for (int r = 0; r < 4; ++r) Co[(size_t)(row0 + r) * ldC + col] = a[r] + bb;
      }
    }
  }
}

extern "C" void kernel_launch(void* const* d_in, const int* in_sizes, int n_in,
                              void* d_out, int out_size, void* d_ws, size_t ws_size,
                              hipStream_t stream) {
  const float* vf = (const float*)d_in[0];
  const float* lf = (const float*)d_in[1];
  const float* Wv = (const float*)d_in[2];
  const float* bv = (const float*)d_in[3];
  const float* Wl = (const float*)d_in[4];
  const float* bl = (const float*)d_in[5];
  const float* Wo = (const float*)d_in[6];
  const float* bo = (const float*)d_in[7];

  constexpr int Bz = 8, L = 2048, D = 768, M = Bz * L, D2 = 2 * D;
  constexpr size_t PLANE = (size_t)M * D;      // 12,582,912 elems
  constexpr size_t WPLANE = (size_t)D * D;     // 589,824 elems

  char* wp = (char*)d_ws;
  auto alloc = [&](size_t bytes) {
    char* p = wp;
    wp += (bytes + 255) & ~(size_t)255;
    return p;
  };
  short* vp16  = (short*)alloc(PLANE * 2);               // 25.2 MB; -> al after step5
  short* P     = (short*)alloc((size_t)Bz * L * L * 2);  // 67.1 MB; -> PT -> out_tmp
  float* invL  = (float*)alloc((size_t)M * 4);           // 64 KB
  float* sums  = (float*)alloc((size_t)M * 4);           // 64 KB

  // direct mode: lp planes in ws, final GEMM writes fp32 straight to d_out.
  size_t need_direct = (size_t)(wp - (char*)d_ws) + 2 * PLANE * 2 + 512;
  bool direct = ws_size >= need_direct;

  short *lp_bf, *lp16;
  if (direct) {
    lp_bf = (short*)alloc(PLANE * 2);
    lp16  = (short*)alloc(PLANE * 2);
  } else {
    lp_bf = (short*)d_out;
    lp16  = lp_bf + PLANE;
  }
  short* lpsT = lp16;    // lp16 dead after sim2
  short* av   = lp_bf;   // lp_bf dead after scale_transpose
  short* al   = vp16;    // vp16 dead after step 5
  // Wo bf16 planes live in the P region tail AFTER step 7 (PT dead):
  short* woh = P + 2 * PLANE;
  short* wol = woh + (size_t)D * D2;
  float* out_tmp = direct ? (float*)d_out : (float*)P;

  // Transient hi/lo planes inside the (not-yet-written) P region (55.0 <= 67.1 MB)
  short* fh  = P;
  short* fl  = P + PLANE;
  short* wvh = P + 2 * PLANE;
  short* wvl = wvh + WPLANE;
  short* wlh = wvl + WPLANE;
  short* wll = wlh + WPLANE;

  constexpr int GF  = (int)(PLANE / 8);           // 1,572,864 groups (feature)
  constexpr int GW  = (int)(WPLANE / 8);          // 73,728 groups (proj weight)
  constexpr int GWO = (int)((size_t)D * D2 / 8);  // 147,456 groups (Wo)

  // 0) zero the row-sum accumulator
  zero_kernel<<<dim3(M / 256), 256, 0, stream>>>(sums, M);

  // 1a) convert vision features + both proj weights (bf16 hi/lo for projg)
  cvt_kernel<<<dim3((GF + 2 * GW) / 256), 256, 0, stream>>>(
      vf, fh, fl, Wv, wvh, wvl, Wl, wlh, wll, GF, GW, GW);

  // 1b) vision projection -> vp16 (fp16)
  projg_kernel<0><<<dim3(768), 256, 0, stream>>>(fh, fl, wvh, wvl, bv, vp16, nullptr);

  // 1c) convert language features
  cvt_kernel<<<dim3(GF / 256), 256, 0, stream>>>(
      lf, fh, fl, nullptr, nullptr, nullptr, nullptr, nullptr, nullptr, GF, 0, 0);

  // 1d) language projection -> lp_bf (bf16) + lp16 (fp16)
  projg_kernel<1><<<dim3(768), 256, 0, stream>>>(fh, fl, wlh, wll, bl, lp_bf, lp16);

  // 2) P = exp(vp16*lp16^T - 20), fused row sums -> sums. 2048 blocks
  sim2_kernel<<<dim3(2048), 256, 0, stream>>>(vp16, lp16, P, sums);

  // 3) invL = 1/sums
  recip_kernel<<<dim3(M / 256), 256, 0, stream>>>(sums, invL, M);

  // 4) lpsT[z][d][i] = lp_bf[z][i][d] * invL  (lp16 slot; lp_bf freed after)
  scale_transpose_kernel<<<dim3(3072), 256, 0, stream>>>(lp_bf, invL, lpsT);

  // 5) aligned_vision = (P @ vp) * invL[row] -> av. B = vp16^T staged (f16->bf16).
  gemm_k<2, true, false, true, false><<<dim3(768), 256, 0, stream>>>(
      P, nullptr, vp16, av, nullptr, invL, 6, 16, 16, L, L, D, D,
      (long)L * L, (long)L * D, (long)L * D, (long)L);

  // 6) P -> P^T in place (per z, 64x64 tile-pair swap). 8192 blocks
  transpose_inplace_kernel<<<dim3(8192), 256, 0, stream>>>(P);

  // 7) aligned_language = P^T @ lps -> al. Both operands plain glds.
  gemm_k<3, false, false, false, false><<<dim3(768), 256, 0, stream>>>(
      P, nullptr, lpsT, al, nullptr, nullptr, 6, 16, 16, L, L, L, D,
      (long)L * L, (long)D * L, (long)L * D, (long)L);

  // 8) convert Wo -> bf16 (P region tail; PT dead now)
  cvt_kernel<<<dim3(GWO / 256), 256, 0, stream>>>(
      Wo, woh, wol, nullptr, nullptr, nullptr, nullptr, nullptr, nullptr, GWO, 0, 0);

  // 9) out = [av | al] @ Wo^T + bo (fp32). B = woh plain bf16 glds.
  gemm_k<4, false, false, false, true><<<dim3(768), 256, 0, stream>>>(
      av, al, woh, out_tmp, bo, nullptr, 6, 16, 128, D2, D, D2, D, 0, 0, 0, 0);

  // 10) out_tmp -> d_out (only when step 9 couldn't write directly)
  if (!direct)
    hipMemcpyAsync(d_out, out_tmp, (size_t)M * D * 4, hipMemcpyDeviceToDevice, stream);
}

// Round 6
// 637.897 us; speedup vs baseline: 1.0958x; 1.0089x over previous
//
#include <hip/hip_runtime.h>
#include <stdint.h>

typedef __attribute__((ext_vector_type(8))) short bf16x8;
typedef __attribute__((ext_vector_type(8))) _Float16 f16x8;
typedef __attribute__((ext_vector_type(4))) float f32x4;

__device__ __forceinline__ float b2f(short h) {
  return __uint_as_float(((unsigned)(unsigned short)h) << 16);
}
__device__ __forceinline__ short f2b(float f) {
  unsigned u = __float_as_uint(f);
  u += 0x7fffu + ((u >> 16) & 1u);
  return (short)(u >> 16);
}
__device__ __forceinline__ short f2h(float f) {
  _Float16 h = (_Float16)f;
  return __builtin_bit_cast(short, h);
}
__device__ __forceinline__ float h2f(short s) {
  return (float)__builtin_bit_cast(_Float16, s);
}

// chunk-swizzle (in shorts): XOR the 8-short chunk index with (r>>1)&3.
__device__ __forceinline__ int swz(int r) { return (r & 6) << 2; }

// async global->LDS, 16 B per lane (global_load_lds_dwordx4)
__device__ __forceinline__ void glds16(const void* g, void* l) {
  __builtin_amdgcn_global_load_lds(
      (const __attribute__((address_space(1))) void*)g,
      (__attribute__((address_space(3))) void*)l, 16, 0, 0);
}

// XCD-aware decode: bijective for total = 8 * RSX * C.
__device__ __forceinline__ void xcd_decode(int C, int RSX, int RPZ,
                                           int& z, int& rowB, int& colB) {
  int id = blockIdx.x;
  int xcd = id & 7, slot = id >> 3;
  int rs = xcd * RSX + slot / C;
  colB = (slot % C) * 128;
  z = rs / RPZ;
  rowB = (rs % RPZ) * 128;
}

// ---------------- one-shot fp32 -> (bf16 hi, bf16 lo) split, 8 elem/thread ----
__global__ __launch_bounds__(256) void cvt_kernel(
    const float* __restrict__ S0, short* __restrict__ H0, short* __restrict__ L0,
    const float* __restrict__ S1, short* __restrict__ H1, short* __restrict__ L1,
    const float* __restrict__ S2, short* __restrict__ H2, short* __restrict__ L2,
    int n0, int n1, int n2) {
  int g = blockIdx.x * 256 + threadIdx.x;
  const float* s;
  short* h;
  short* l;
  if (g < n0) {
    s = S0 + (size_t)g * 8;
    h = H0 + (size_t)g * 8;
    l = L0 + (size_t)g * 8;
  } else if (g < n0 + n1) {
    size_t t = (size_t)(g - n0);
    s = S1 + t * 8;
    h = H1 + t * 8;
    l = L1 + t * 8;
  } else {
    size_t t = (size_t)(g - n0 - n1);
    s = S2 + t * 8;
    h = H2 + t * 8;
    l = L2 + t * 8;
  }
  float4 v0 = *reinterpret_cast<const float4*>(s);
  float4 v1 = *reinterpret_cast<const float4*>(s + 4);
  float vv[8] = {v0.x, v0.y, v0.z, v0.w, v1.x, v1.y, v1.z, v1.w};
  bf16x8 th, tl;
#pragma unroll
  for (int j = 0; j < 8; ++j) {
    short hh = f2b(vv[j]);
    th[j] = hh;
    tl[j] = f2b(vv[j] - b2f(hh));
  }
  *reinterpret_cast<bf16x8*>(h) = th;
  *reinterpret_cast<bf16x8*>(l) = tl;
}

// ---------------- zero / reciprocal helpers ----------------
__global__ __launch_bounds__(256) void zero_kernel(float* __restrict__ p, int n) {
  int i = blockIdx.x * 256 + threadIdx.x;
  if (i < n) p[i] = 0.f;
}
__global__ __launch_bounds__(256) void recip_kernel(const float* __restrict__ s,
                                                    float* __restrict__ invL, int n) {
  int i = blockIdx.x * 256 + threadIdx.x;
  if (i < n) invL[i] = 1.0f / s[i];
}

// ---------------- 64x64-tile transpose of a [2048][768] plane per z ----------
// SCALE=1: src bf16, dst[d][i] = f2b(b2f(src[i][d]) * invL[z*2048+i])  (lpsT)
// SCALE=0: src f16,  dst[d][i] = f2b(h2f(src[i][d]))                  (vpT)
template <bool SCALE>
__global__ __launch_bounds__(256) void xpose_kernel(
    const short* __restrict__ src0, const float* __restrict__ invL,
    short* __restrict__ dst0) {
  __shared__ alignas(16) short T[64 * 64];
  int id = blockIdx.x;
  int z = id / 384, r = id % 384;
  int it = r / 12, dt = r % 12;
  int i0 = it * 64, d0 = dt * 64;
  const short* src = src0 + (size_t)z * 2048 * 768;
  const float* Lz = SCALE ? (invL + (size_t)z * 2048) : nullptr;
  int t = threadIdx.x;
#pragma unroll
  for (int q = 0; q < 2; ++q) {
    int v = t * 2 + q;
    int ii = v >> 3, dc = (v & 7) * 8;
    bf16x8 x = *reinterpret_cast<const bf16x8*>(&src[(size_t)(i0 + ii) * 768 + d0 + dc]);
    bf16x8 y;
    if constexpr (SCALE) {
      float s = Lz[i0 + ii];
#pragma unroll
      for (int j = 0; j < 8; ++j) y[j] = f2b(b2f(x[j]) * s);
    } else {
#pragma unroll
      for (int j = 0; j < 8; ++j) y[j] = f2b(h2f(x[j]));
    }
    *reinterpret_cast<bf16x8*>(&T[ii * 64 + (dc ^ ((ii & 7) << 3))]) = y;
  }
  __syncthreads();
  short* dst = dst0 + (size_t)z * 768 * 2048;
#pragma unroll
  for (int q = 0; q < 2; ++q) {
    int v = t * 2 + q;
    int dd = v >> 3, is = (v & 7) * 8;
    bf16x8 y;
#pragma unroll
    for (int s2 = 0; s2 < 8; ++s2) {
      int rr = is + s2;
      y[s2] = T[rr * 64 + (dd ^ ((rr & 7) << 3))];
    }
    *reinterpret_cast<bf16x8*>(&dst[(size_t)(d0 + dd) * 2048 + i0 + is]) = y;
  }
}

// ---------------- in-place per-z transpose of P (2048x2048), tile-pair swap ----
__global__ __launch_bounds__(256) void transpose_inplace_kernel(short* __restrict__ P) {
  __shared__ alignas(16) short Ta[64 * 64];
  __shared__ alignas(16) short Tb[64 * 64];
  int id = blockIdx.x;
  int z = id >> 10, r = id & 1023;
  int a = r >> 5, b = r & 31;
  if (a > b) return;
  short* Pz = P + (size_t)z * 2048 * 2048;
  int t = threadIdx.x;
#pragma unroll
  for (int q = 0; q < 2; ++q) {
    int v = t * 2 + q;
    int ii = v >> 3, cc = (v & 7) * 8;
    bf16x8 x = *reinterpret_cast<const bf16x8*>(&Pz[(size_t)(a * 64 + ii) * 2048 + b * 64 + cc]);
    *reinterpret_cast<bf16x8*>(&Ta[ii * 64 + (cc ^ ((ii & 7) << 3))]) = x;
    if (a != b) {
      bf16x8 y = *reinterpret_cast<const bf16x8*>(&Pz[(size_t)(b * 64 + ii) * 2048 + a * 64 + cc]);
      *reinterpret_cast<bf16x8*>(&Tb[ii * 64 + (cc ^ ((ii & 7) << 3))]) = y;
    }
  }
  __syncthreads();
#pragma unroll
  for (int q = 0; q < 2; ++q) {
    int v = t * 2 + q;
    int rr = v >> 3, cs = (v & 7) * 8;
    bf16x8 x, y;
#pragma unroll
    for (int s2 = 0; s2 < 8; ++s2) {
      int rs = cs + s2;
      x[s2] = Ta[rs * 64 + (rr ^ ((rs & 7) << 3))];
      if (a != b) y[s2] = Tb[rs * 64 + (rr ^ ((rs & 7) << 3))];
    }
    *reinterpret_cast<bf16x8*>(&Pz[(size_t)(b * 64 + rr) * 2048 + a * 64 + cs]) = x;
    if (a != b)
      *reinterpret_cast<bf16x8*>(&Pz[(size_t)(a * 64 + rr) * 2048 + b * 64 + cs]) = y;
  }
}

// =================================================================================
// projg: C = A @ B^T + bias, 3-pass split precision, glds w/ pre-swizzled source.
// OM=0: write f16 plane only (Ch). OM=1: write bf16 plane (Ch) + f16 plane (Cl).
// =================================================================================
template <int OM>
__global__ __launch_bounds__(256) void projg_kernel(
    const short* __restrict__ Ah, const short* __restrict__ Al,
    const short* __restrict__ Bh, const short* __restrict__ Bl,
    const float* __restrict__ bias,
    short* __restrict__ Ch, short* __restrict__ Cl) {
  __shared__ alignas(16) short AsH[128 * 32];
  __shared__ alignas(16) short AsL[128 * 32];
  __shared__ alignas(16) short BsH[128 * 32];
  __shared__ alignas(16) short BsL[128 * 32];
  const int tid = threadIdx.x;
  int z, rowBase, colBase;
  xcd_decode(6, 16, 128, z, rowBase, colBase);
  (void)z;
  const int lane = tid & 63;
  const int ln = lane & 15;
  const int qd = lane >> 4;
  const int w = tid >> 6;
  const int wr = w >> 1, wc = w & 1;

  f32x4 acc[4][4];
#pragma unroll
  for (int i = 0; i < 4; ++i)
#pragma unroll
    for (int j = 0; j < 4; ++j) acc[i][j] = 0.f;

  for (int kb = 0; kb < 768; kb += 32) {
#pragma unroll
    for (int q = 0; q < 2; ++q) {
      int c = q * 256 + tid;
      int r = c >> 2;
      int k0 = ((c & 3) << 3) ^ swz(r);
      size_t ao = (size_t)(rowBase + r) * 768 + kb + k0;
      size_t bo = (size_t)(colBase + r) * 768 + kb + k0;
      glds16(&Ah[ao], &AsH[c * 8]);
      glds16(&Al[ao], &AsL[c * 8]);
      glds16(&Bh[bo], &BsH[c * 8]);
      glds16(&Bl[bo], &BsL[c * 8]);
    }
    __syncthreads();
    bf16x8 ah[4], bh[4], t[4];
#pragma unroll
    for (int rt = 0; rt < 4; ++rt) {
      int m = wr * 64 + rt * 16 + ln;
      ah[rt] = *reinterpret_cast<const bf16x8*>(&AsH[m * 32 + ((qd * 8) ^ swz(m))]);
    }
#pragma unroll
    for (int ct = 0; ct < 4; ++ct) {
      int n = wc * 64 + ct * 16 + ln;
      bh[ct] = *reinterpret_cast<const bf16x8*>(&BsH[n * 32 + ((qd * 8) ^ swz(n))]);
    }
#pragma unroll
    for (int rt = 0; rt < 4; ++rt)
#pragma unroll
      for (int ct = 0; ct < 4; ++ct)
        acc[rt][ct] = __builtin_amdgcn_mfma_f32_16x16x32_bf16(ah[rt], bh[ct], acc[rt][ct], 0, 0, 0);
#pragma unroll
    for (int rt = 0; rt < 4; ++rt) {
      int m = wr * 64 + rt * 16 + ln;
      t[rt] = *reinterpret_cast<const bf16x8*>(&AsL[m * 32 + ((qd * 8) ^ swz(m))]);
    }
#pragma unroll
    for (int rt = 0; rt < 4; ++rt)
#pragma unroll
      for (int ct = 0; ct < 4; ++ct)
        acc[rt][ct] = __builtin_amdgcn_mfma_f32_16x16x32_bf16(t[rt], bh[ct], acc[rt][ct], 0, 0, 0);
#pragma unroll
    for (int ct = 0; ct < 4; ++ct) {
      int n = wc * 64 + ct * 16 + ln;
      t[ct] = *reinterpret_cast<const bf16x8*>(&BsL[n * 32 + ((qd * 8) ^ swz(n))]);
    }
#pragma unroll
    for (int rt = 0; rt < 4; ++rt)
#pragma unroll
      for (int ct = 0; ct < 4; ++ct)
        acc[rt][ct] = __builtin_amdgcn_mfma_f32_16x16x32_bf16(ah[rt], t[ct], acc[rt][ct], 0, 0, 0);
    __syncthreads();
  }

#pragma unroll
  for (int rt = 0; rt < 4; ++rt) {
    int row0 = rowBase + wr * 64 + rt * 16 + qd * 4;
#pragma unroll
    for (int ct = 0; ct < 4; ++ct) {
      int col = colBase + wc * 64 + ct * 16 + ln;
      float bb = bias[col];
      f32x4 a = acc[rt][ct];
#pragma unroll
      for (int r = 0; r < 4; ++r) {
        float val = a[r] + bb;
        if constexpr (OM == 0) {
          Ch[(size_t)(row0 + r) * 768 + col] = f2h(val);
        } else {
          Ch[(size_t)(row0 + r) * 768 + col] = f2b(val);
          Cl[(size_t)(row0 + r) * 768 + col] = f2h(val);
        }
      }
    }
  }
}

// =================================================================================
// sim2: P = exp(vp16*lp16^T - 20), single fp16 MFMA pass, glds staging w/
// pre-swizzled source. Epilogue: fused bf16-rounded row sums -> atomicAdd(S).
// =================================================================================
__global__ __launch_bounds__(256) void sim2_kernel(const short* __restrict__ vp,
                                                   const short* __restrict__ lp,
                                                   short* __restrict__ P,
                                                   float* __restrict__ S) {
  __shared__ alignas(16) short As[128 * 32];
  __shared__ alignas(16) short Bs[128 * 32];
  const int tid = threadIdx.x;
  int z, rowBase, colBase;
  xcd_decode(16, 16, 16, z, rowBase, colBase);
  const short* Az = vp + (size_t)z * 2048 * 768;
  const short* Bz = lp + (size_t)z * 2048 * 768;
  const int lane = tid & 63;
  const int ln = lane & 15;
  const int qd = lane >> 4;
  const int w = tid >> 6;
  const int wr = w >> 1, wc = w & 1;

  f32x4 acc[4][4];
#pragma unroll
  for (int i = 0; i < 4; ++i)
#pragma unroll
    for (int j = 0; j < 4; ++j) acc[i][j] = 0.f;

  for (int kb = 0; kb < 768; kb += 32) {
#pragma unroll
    for (int q = 0; q < 2; ++q) {
      int c = q * 256 + tid;
      int r = c >> 2;
      int k0 = ((c & 3) << 3) ^ swz(r);
      glds16(&Az[(size_t)(rowBase + r) * 768 + kb + k0], &As[c * 8]);
      glds16(&Bz[(size_t)(colBase + r) * 768 + kb + k0], &Bs[c * 8]);
    }
    __syncthreads();
    f16x8 af[4], bf[4];
#pragma unroll
    for (int rt = 0; rt < 4; ++rt) {
      int m = wr * 64 + rt * 16 + ln;
      af[rt] = *reinterpret_cast<const f16x8*>(&As[m * 32 + ((qd * 8) ^ swz(m))]);
    }
#pragma unroll
    for (int ct = 0; ct < 4; ++ct) {
      int n = wc * 64 + ct * 16 + ln;
      bf[ct] = *reinterpret_cast<const f16x8*>(&Bs[n * 32 + ((qd * 8) ^ swz(n))]);
    }
#pragma unroll
    for (int rt = 0; rt < 4; ++rt)
#pragma unroll
      for (int ct = 0; ct < 4; ++ct)
        acc[rt][ct] = __builtin_amdgcn_mfma_f32_16x16x32_f16(af[rt], bf[ct], acc[rt][ct], 0, 0, 0);
    __syncthreads();
  }

  short* Pz = P + (size_t)z * 2048 * 2048;
  float* Sz = S + (size_t)z * 2048;
#pragma unroll
  for (int rt = 0; rt < 4; ++rt) {
    int row0 = rowBase + wr * 64 + rt * 16 + qd * 4;
    float rowp[4] = {0.f, 0.f, 0.f, 0.f};
#pragma unroll
    for (int ct = 0; ct < 4; ++ct) {
      int col = colBase + wc * 64 + ct * 16 + ln;
      f32x4 a = acc[rt][ct];
#pragma unroll
      for (int r = 0; r < 4; ++r) {
        short h = f2b(__expf(a[r] - 20.0f));
        Pz[(size_t)(row0 + r) * 2048 + col] = h;
        rowp[r] += b2f(h);
      }
    }
#pragma unroll
    for (int r = 0; r < 4; ++r) {
      float v = rowp[r];
      v += __shfl_xor(v, 1);
      v += __shfl_xor(v, 2);
      v += __shfl_xor(v, 4);
      v += __shfl_xor(v, 8);
      if (ln == 0) atomicAdd(&Sz[row0 + r], v);
    }
  }
}

// =================================================================================
// gemm_k: C[m,n] = sum_k A[m,k]*B[n,k], bf16, both operands plain glds
// (pre-swizzled source). DUALA: A split 768|768.
// MODE 2: bf16 = acc*invL[row]; MODE 3: bf16 = acc; MODE 4: fp32 = acc+bias[col]
// =================================================================================
template <int MODE, bool DUALA>
__global__ __launch_bounds__(256) void gemm_k(const short* __restrict__ A,
                                              const short* __restrict__ A2,
                                              const short* __restrict__ B,
                                              void* __restrict__ C,
                                              const float* __restrict__ bias,
                                              const float* __restrict__ invL,
                                              int C_, int RSX_, int RPZ_,
                                              int K, int ldA, int ldB, int ldC,
                                              long sA, long sB, long sC, long sL) {
  __shared__ alignas(16) short As[128 * 32];
  __shared__ alignas(16) short Bs[128 * 32];
  const int tid = threadIdx.x;
  int z, rowBase, colBase;
  xcd_decode(C_, RSX_, RPZ_, z, rowBase, colBase);
  const short* Az = A + (size_t)z * sA;
  const short* Bz = B + (size_t)z * sB;
  const float* Lz = invL ? (invL + (size_t)z * sL) : nullptr;
  const int lane = tid & 63;
  const int ln = lane & 15;
  const int qd = lane >> 4;
  const int w = tid >> 6;
  const int wr = w >> 1, wc = w & 1;

  f32x4 acc[4][4];
#pragma unroll
  for (int i = 0; i < 4; ++i)
#pragma unroll
    for (int j = 0; j < 4; ++j) acc[i][j] = 0.f;

  for (int kb = 0; kb < K; kb += 32) {
#pragma unroll
    for (int q = 0; q < 2; ++q) {
      int c = q * 256 + tid;
      int r = c >> 2;
      int k0 = ((c & 3) << 3) ^ swz(r);
      int kk = kb + k0;
      const short* src;
      if constexpr (DUALA) {
        src = (kk < 768) ? &Az[(size_t)(rowBase + r) * 768 + kk]
                         : &A2[(size_t)(rowBase + r) * 768 + kk - 768];
      } else {
        src = &Az[(size_t)(rowBase + r) * ldA + kk];
      }
      glds16(src, &As[c * 8]);
      glds16(&Bz[(size_t)(colBase + r) * ldB + kb + k0], &Bs[c * 8]);
    }
    __syncthreads();
    bf16x8 af[4], bfv[4];
#pragma unroll
    for (int rt = 0; rt < 4; ++rt) {
      int m = wr * 64 + rt * 16 + ln;
      af[rt] = *reinterpret_cast<const bf16x8*>(&As[m * 32 + ((qd * 8) ^ swz(m))]);
    }
#pragma unroll
    for (int ct = 0; ct < 4; ++ct) {
      int n = wc * 64 + ct * 16 + ln;
      bfv[ct] = *reinterpret_cast<const bf16x8*>(&Bs[n * 32 + ((qd * 8) ^ swz(n))]);
    }
#pragma unroll
    for (int rt = 0; rt < 4; ++rt)
#pragma unroll
      for (int ct = 0; ct < 4; ++ct)
        acc[rt][ct] =
            __builtin_amdgcn_mfma_f32_16x16x32_bf16(af[rt], bfv[ct], acc[rt][ct], 0, 0, 0);
    __syncthreads();
  }

#pragma unroll
  for (int rt = 0; rt < 4; ++rt) {
    int row0 = rowBase + wr * 64 + rt * 16 + qd * 4;
#pragma unroll
    for (int ct = 0; ct < 4; ++ct) {
      int col = colBase + wc * 64 + ct * 16 + ln;
      f32x4 a = acc[rt][ct];
      if constexpr (MODE == 2) {
        short* Co = (short*)C + (size_t)z * sC;
#pragma unroll
        for (int r = 0; r < 4; ++r)
          Co[(size_t)(row0 + r) * ldC + col] = f2b(a[r] * Lz[row0 + r]);
      } else if constexpr (MODE == 3) {
        short* Co = (short*)C + (size_t)z * sC;
#pragma unroll
        for (int r = 0; r < 4; ++r) Co[(size_t)(row0 + r) * ldC + col] = f2b(a[r]);
      } else {  // MODE 4
        float* Co = (float*)C + (size_t)z * sC;
        float bb = bias[col];
#pragma unroll
        for (int r = 0; r < 4; ++r) Co[(size_t)(row0 + r) * ldC + col] = a[r] + bb;
      }
    }
  }
}

extern "C" void kernel_launch(void* const* d_in, const int* in_sizes, int n_in,
                              void* d_out, int out_size, void* d_ws, size_t ws_size,
                              hipStream_t stream) {
  const float* vf = (const float*)d_in[0];
  const float* lf = (const float*)d_in[1];
  const float* Wv = (const float*)d_in[2];
  const float* bv = (const float*)d_in[3];
  const float* Wl = (const float*)d_in[4];
  const float* bl = (const float*)d_in[5];
  const float* Wo = (const float*)d_in[6];
  const float* bo = (const float*)d_in[7];

  constexpr int Bz = 8, L = 2048, D = 768, M = Bz * L, D2 = 2 * D;
  constexpr size_t PLANE = (size_t)M * D;      // 12,582,912 elems
  constexpr size_t WPLANE = (size_t)D * D;     // 589,824 elems

  char* wp = (char*)d_ws;
  auto alloc = [&](size_t bytes) {
    char* p = wp;
    wp += (bytes + 255) & ~(size_t)255;
    return p;
  };
  short* vp16  = (short*)alloc(PLANE * 2);               // 25.2 MB; -> av after xpose
  short* P     = (short*)alloc((size_t)Bz * L * L * 2);  // 67.1 MB; -> PT -> out_tmp
  float* invL  = (float*)alloc((size_t)M * 4);           // 64 KB
  float* sums  = (float*)alloc((size_t)M * 4);           // 64 KB

  // direct mode: lp planes in ws, final GEMM writes fp32 straight to d_out.
  size_t need_direct = (size_t)(wp - (char*)d_ws) + 2 * PLANE * 2 + 512;
  bool direct = ws_size >= need_direct;

  short *lp_bf, *lp16;
  if (direct) {
    lp_bf = (short*)alloc(PLANE * 2);
    lp16  = (short*)alloc(PLANE * 2);
  } else {
    lp_bf = (short*)d_out;
    lp16  = lp_bf + PLANE;
  }
  short* lpsT = lp16;    // lp16 dead after sim2
  short* vpT  = lp_bf;   // lp_bf dead after xpose<1> (step 4)
  short* av   = vp16;    // vp16 dead after xpose<0> (step 4b)
  short* al   = lp_bf;   // vpT dead after step 5; step 7 writes here
  // Wo bf16 planes live in the P region tail (PT dead after step 7):
  short* woh = P + 2 * PLANE;
  short* wol = woh + (size_t)D * D2;
  float* out_tmp = direct ? (float*)d_out : (float*)P;

  // Transient hi/lo planes inside the (not-yet-written) P region (55.0 <= 67.1 MB)
  short* fh  = P;
  short* fl  = P + PLANE;
  short* wvh = P + 2 * PLANE;
  short* wvl = wvh + WPLANE;
  short* wlh = wvl + WPLANE;
  short* wll = wlh + WPLANE;

  constexpr int GF  = (int)(PLANE / 8);           // 1,572,864 groups (feature)
  constexpr int GW  = (int)(WPLANE / 8);          // 73,728 groups (proj weight)
  constexpr int GWO = (int)((size_t)D * D2 / 8);  // 147,456 groups (Wo)

  // 0) zero the row-sum accumulator
  zero_kernel<<<dim3(M / 256), 256, 0, stream>>>(sums, M);

  // 1a) convert vision features + both proj weights (bf16 hi/lo for projg)
  cvt_kernel<<<dim3((GF + 2 * GW) / 256), 256, 0, stream>>>(
      vf, fh, fl, Wv, wvh, wvl, Wl, wlh, wll, GF, GW, GW);

  // 1b) vision projection -> vp16 (fp16)
  projg_kernel<0><<<dim3(768), 256, 0, stream>>>(fh, fl, wvh, wvl, bv, vp16, nullptr);

  // 1c) convert language features
  cvt_kernel<<<dim3(GF / 256), 256, 0, stream>>>(
      lf, fh, fl, nullptr, nullptr, nullptr, nullptr, nullptr, nullptr, GF, 0, 0);

  // 1d) language projection -> lp_bf (bf16) + lp16 (fp16)
  projg_kernel<1><<<dim3(768), 256, 0, stream>>>(fh, fl, wlh, wll, bl, lp_bf, lp16);

  // 2) P = exp(vp16*lp16^T - 20), fused row sums -> sums. 2048 blocks
  sim2_kernel<<<dim3(2048), 256, 0, stream>>>(vp16, lp16, P, sums);

  // 3) invL = 1/sums
  recip_kernel<<<dim3(M / 256), 256, 0, stream>>>(sums, invL, M);

  // 4) lpsT[z][d][i] = lp_bf[z][i][d] * invL  (-> lp16 slot)
  xpose_kernel<true><<<dim3(3072), 256, 0, stream>>>(lp_bf, invL, lpsT);

  // 4b) vpT[z][d][i] = bf16(vp16[z][i][d])    (-> lp_bf slot)
  xpose_kernel<false><<<dim3(3072), 256, 0, stream>>>(vp16, nullptr, vpT);

  // 5) aligned_vision = (P @ vp) * invL[row] -> av (vp16 slot). Both plain glds.
  gemm_k<2, false><<<dim3(768), 256, 0, stream>>>(
      P, nullptr, vpT, av, nullptr, invL, 6, 16, 16, L, L, L, D,
      (long)L * L, (long)D * L, (long)L * D, (long)L);

  // 6) P -> P^T in place (per z, 64x64 tile-pair swap). 8192 blocks
  transpose_inplace_kernel<<<dim3(8192), 256, 0, stream>>>(P);

  // 7) aligned_language = P^T @ lps -> al (lp_bf slot). Both plain glds.
  gemm_k<3, false><<<dim3(768), 256, 0, stream>>>(
      P, nullptr, lpsT, al, nullptr, nullptr, 6, 16, 16, L, L, L, D,
      (long)L * L, (long)D * L, (long)L * D, (long)L);

  // 8) convert Wo -> bf16 (P region tail; PT dead now)
  cvt_kernel<<<dim3(GWO / 256), 256, 0, stream>>>(
      Wo, woh, wol, nullptr, nullptr, nullptr, nullptr, nullptr, nullptr, GWO, 0, 0);

  // 9) out = [av | al] @ Wo^T + bo (fp32). B = woh plain bf16 glds.
  gemm_k<4, true><<<dim3(768), 256, 0, stream>>>(
      av, al, woh, out_tmp, bo, nullptr, 6, 16, 128, D2, D, D2, D, 0, 0, 0, 0);

  // 10) out_tmp -> d_out (only when step 9 couldn't write directly)
  if (!direct)
    hipMemcpyAsync(d_out, out_tmp, (size_t)M * D * 4, hipMemcpyDeviceToDevice, stream);
}

// Round 7
// 619.852 us; speedup vs baseline: 1.1277x; 1.0291x over previous
//
#include <hip/hip_runtime.h>
#include <stdint.h>

typedef __attribute__((ext_vector_type(8))) short bf16x8;
typedef __attribute__((ext_vector_type(8))) _Float16 f16x8;
typedef __attribute__((ext_vector_type(4))) float f32x4;

__device__ __forceinline__ float b2f(short h) {
  return __uint_as_float(((unsigned)(unsigned short)h) << 16);
}
__device__ __forceinline__ short f2b(float f) {
  unsigned u = __float_as_uint(f);
  u += 0x7fffu + ((u >> 16) & 1u);
  return (short)(u >> 16);
}
__device__ __forceinline__ short f2h(float f) {
  _Float16 h = (_Float16)f;
  return __builtin_bit_cast(short, h);
}
__device__ __forceinline__ float h2f(short s) {
  return (float)__builtin_bit_cast(_Float16, s);
}

// chunk-swizzle (in shorts): XOR the 8-short chunk index with (r>>1)&3.
__device__ __forceinline__ int swz(int r) { return (r & 6) << 2; }

// async global->LDS, 16 B per lane (global_load_lds_dwordx4)
__device__ __forceinline__ void glds16(const void* g, void* l) {
  __builtin_amdgcn_global_load_lds(
      (const __attribute__((address_space(1))) void*)g,
      (__attribute__((address_space(3))) void*)l, 16, 0, 0);
}

// XCD-aware decode: bijective for total = 8 * RSX * C.
__device__ __forceinline__ void xcd_decode(int C, int RSX, int RPZ,
                                           int& z, int& rowB, int& colB) {
  int id = blockIdx.x;
  int xcd = id & 7, slot = id >> 3;
  int rs = xcd * RSX + slot / C;
  colB = (slot % C) * 128;
  z = rs / RPZ;
  rowB = (rs % RPZ) * 128;
}

// ---------------- one-shot fp32 -> (bf16 hi, bf16 lo) split, 8 elem/thread ----
__global__ __launch_bounds__(256) void cvt_kernel(
    const float* __restrict__ S0, short* __restrict__ H0, short* __restrict__ L0,
    const float* __restrict__ S1, short* __restrict__ H1, short* __restrict__ L1,
    const float* __restrict__ S2, short* __restrict__ H2, short* __restrict__ L2,
    int n0, int n1, int n2) {
  int g = blockIdx.x * 256 + threadIdx.x;
  const float* s;
  short* h;
  short* l;
  if (g < n0) {
    s = S0 + (size_t)g * 8;
    h = H0 + (size_t)g * 8;
    l = L0 + (size_t)g * 8;
  } else if (g < n0 + n1) {
    size_t t = (size_t)(g - n0);
    s = S1 + t * 8;
    h = H1 + t * 8;
    l = L1 + t * 8;
  } else {
    size_t t = (size_t)(g - n0 - n1);
    s = S2 + t * 8;
    h = H2 + t * 8;
    l = L2 + t * 8;
  }
  float4 v0 = *reinterpret_cast<const float4*>(s);
  float4 v1 = *reinterpret_cast<const float4*>(s + 4);
  float vv[8] = {v0.x, v0.y, v0.z, v0.w, v1.x, v1.y, v1.z, v1.w};
  bf16x8 th, tl;
#pragma unroll
  for (int j = 0; j < 8; ++j) {
    short hh = f2b(vv[j]);
    th[j] = hh;
    tl[j] = f2b(vv[j] - b2f(hh));
  }
  *reinterpret_cast<bf16x8*>(h) = th;
  *reinterpret_cast<bf16x8*>(l) = tl;
}

// ---------------- zero / reciprocal helpers ----------------
__global__ __launch_bounds__(256) void zero_kernel(float* __restrict__ p, int n) {
  int i = blockIdx.x * 256 + threadIdx.x;
  if (i < n) p[i] = 0.f;
}
__global__ __launch_bounds__(256) void recip_kernel(const float* __restrict__ s,
                                                    float* __restrict__ invL, int n) {
  int i = blockIdx.x * 256 + threadIdx.x;
  if (i < n) invL[i] = 1.0f / s[i];
}

// ---------------- 64x64-tile transpose of a [2048][768] plane per z ----------
// SCALE=1: src bf16, dst[d][i] = f2b(b2f(src[i][d]) * invL[z*2048+i])  (lpsT)
// SCALE=0: src f16,  dst[d][i] = f2b(h2f(src[i][d]))                  (vpT)
template <bool SCALE>
__global__ __launch_bounds__(256) void xpose_kernel(
    const short* __restrict__ src0, const float* __restrict__ invL,
    short* __restrict__ dst0) {
  __shared__ alignas(16) short T[64 * 64];
  int id = blockIdx.x;
  int z = id / 384, r = id % 384;
  int it = r / 12, dt = r % 12;
  int i0 = it * 64, d0 = dt * 64;
  const short* src = src0 + (size_t)z * 2048 * 768;
  const float* Lz = SCALE ? (invL + (size_t)z * 2048) : nullptr;
  int t = threadIdx.x;
#pragma unroll
  for (int q = 0; q < 2; ++q) {
    int v = t * 2 + q;
    int ii = v >> 3, dc = (v & 7) * 8;
    bf16x8 x = *reinterpret_cast<const bf16x8*>(&src[(size_t)(i0 + ii) * 768 + d0 + dc]);
    bf16x8 y;
    if constexpr (SCALE) {
      float s = Lz[i0 + ii];
#pragma unroll
      for (int j = 0; j < 8; ++j) y[j] = f2b(b2f(x[j]) * s);
    } else {
#pragma unroll
      for (int j = 0; j < 8; ++j) y[j] = f2b(h2f(x[j]));
    }
    *reinterpret_cast<bf16x8*>(&T[ii * 64 + (dc ^ ((ii & 7) << 3))]) = y;
  }
  __syncthreads();
  short* dst = dst0 + (size_t)z * 768 * 2048;
#pragma unroll
  for (int q = 0; q < 2; ++q) {
    int v = t * 2 + q;
    int dd = v >> 3, is = (v & 7) * 8;
    bf16x8 y;
#pragma unroll
    for (int s2 = 0; s2 < 8; ++s2) {
      int rr = is + s2;
      y[s2] = T[rr * 64 + (dd ^ ((rr & 7) << 3))];
    }
    *reinterpret_cast<bf16x8*>(&dst[(size_t)(d0 + dd) * 2048 + i0 + is]) = y;
  }
}

// ---------------- in-place per-z transpose of P (2048x2048), tile-pair swap ----
__global__ __launch_bounds__(256) void transpose_inplace_kernel(short* __restrict__ P) {
  __shared__ alignas(16) short Ta[64 * 64];
  __shared__ alignas(16) short Tb[64 * 64];
  int id = blockIdx.x;
  int z = id >> 10, r = id & 1023;
  int a = r >> 5, b = r & 31;
  if (a > b) return;
  short* Pz = P + (size_t)z * 2048 * 2048;
  int t = threadIdx.x;
#pragma unroll
  for (int q = 0; q < 2; ++q) {
    int v = t * 2 + q;
    int ii = v >> 3, cc = (v & 7) * 8;
    bf16x8 x = *reinterpret_cast<const bf16x8*>(&Pz[(size_t)(a * 64 + ii) * 2048 + b * 64 + cc]);
    *reinterpret_cast<bf16x8*>(&Ta[ii * 64 + (cc ^ ((ii & 7) << 3))]) = x;
    if (a != b) {
      bf16x8 y = *reinterpret_cast<const bf16x8*>(&Pz[(size_t)(b * 64 + ii) * 2048 + a * 64 + cc]);
      *reinterpret_cast<bf16x8*>(&Tb[ii * 64 + (cc ^ ((ii & 7) << 3))]) = y;
    }
  }
  __syncthreads();
#pragma unroll
  for (int q = 0; q < 2; ++q) {
    int v = t * 2 + q;
    int rr = v >> 3, cs = (v & 7) * 8;
    bf16x8 x, y;
#pragma unroll
    for (int s2 = 0; s2 < 8; ++s2) {
      int rs = cs + s2;
      x[s2] = Ta[rs * 64 + (rr ^ ((rs & 7) << 3))];
      if (a != b) y[s2] = Tb[rs * 64 + (rr ^ ((rs & 7) << 3))];
    }
    *reinterpret_cast<bf16x8*>(&Pz[(size_t)(b * 64 + rr) * 2048 + a * 64 + cs]) = x;
    if (a != b)
      *reinterpret_cast<bf16x8*>(&Pz[(size_t)(a * 64 + rr) * 2048 + b * 64 + cs]) = y;
  }
}

// =================================================================================
// projg: C = A @ B^T + bias, 3-pass split precision, glds w/ pre-swizzled source.
// OM=0: write f16 plane only (Ch). OM=1: write bf16 plane (Ch) + f16 plane (Cl).
// (kept single-buffered: dbuf would need 64 KB LDS -> 2 blocks/CU, m132 regression)
// =================================================================================
template <int OM>
__global__ __launch_bounds__(256) void projg_kernel(
    const short* __restrict__ Ah, const short* __restrict__ Al,
    const short* __restrict__ Bh, const short* __restrict__ Bl,
    const float* __restrict__ bias,
    short* __restrict__ Ch, short* __restrict__ Cl) {
  __shared__ alignas(16) short AsH[128 * 32];
  __shared__ alignas(16) short AsL[128 * 32];
  __shared__ alignas(16) short BsH[128 * 32];
  __shared__ alignas(16) short BsL[128 * 32];
  const int tid = threadIdx.x;
  int z, rowBase, colBase;
  xcd_decode(6, 16, 128, z, rowBase, colBase);
  (void)z;
  const int lane = tid & 63;
  const int ln = lane & 15;
  const int qd = lane >> 4;
  const int w = tid >> 6;
  const int wr = w >> 1, wc = w & 1;

  f32x4 acc[4][4];
#pragma unroll
  for (int i = 0; i < 4; ++i)
#pragma unroll
    for (int j = 0; j < 4; ++j) acc[i][j] = 0.f;

  for (int kb = 0; kb < 768; kb += 32) {
#pragma unroll
    for (int q = 0; q < 2; ++q) {
      int c = q * 256 + tid;
      int r = c >> 2;
      int k0 = ((c & 3) << 3) ^ swz(r);
      size_t ao = (size_t)(rowBase + r) * 768 + kb + k0;
      size_t bo = (size_t)(colBase + r) * 768 + kb + k0;
      glds16(&Ah[ao], &AsH[c * 8]);
      glds16(&Al[ao], &AsL[c * 8]);
      glds16(&Bh[bo], &BsH[c * 8]);
      glds16(&Bl[bo], &BsL[c * 8]);
    }
    __syncthreads();
    bf16x8 ah[4], bh[4], t[4];
#pragma unroll
    for (int rt = 0; rt < 4; ++rt) {
      int m = wr * 64 + rt * 16 + ln;
      ah[rt] = *reinterpret_cast<const bf16x8*>(&AsH[m * 32 + ((qd * 8) ^ swz(m))]);
    }
#pragma unroll
    for (int ct = 0; ct < 4; ++ct) {
      int n = wc * 64 + ct * 16 + ln;
      bh[ct] = *reinterpret_cast<const bf16x8*>(&BsH[n * 32 + ((qd * 8) ^ swz(n))]);
    }
#pragma unroll
    for (int rt = 0; rt < 4; ++rt)
#pragma unroll
      for (int ct = 0; ct < 4; ++ct)
        acc[rt][ct] = __builtin_amdgcn_mfma_f32_16x16x32_bf16(ah[rt], bh[ct], acc[rt][ct], 0, 0, 0);
#pragma unroll
    for (int rt = 0; rt < 4; ++rt) {
      int m = wr * 64 + rt * 16 + ln;
      t[rt] = *reinterpret_cast<const bf16x8*>(&AsL[m * 32 + ((qd * 8) ^ swz(m))]);
    }
#pragma unroll
    for (int rt = 0; rt < 4; ++rt)
#pragma unroll
      for (int ct = 0; ct < 4; ++ct)
        acc[rt][ct] = __builtin_amdgcn_mfma_f32_16x16x32_bf16(t[rt], bh[ct], acc[rt][ct], 0, 0, 0);
#pragma unroll
    for (int ct = 0; ct < 4; ++ct) {
      int n = wc * 64 + ct * 16 + ln;
      t[ct] = *reinterpret_cast<const bf16x8*>(&BsL[n * 32 + ((qd * 8) ^ swz(n))]);
    }
#pragma unroll
    for (int rt = 0; rt < 4; ++rt)
#pragma unroll
      for (int ct = 0; ct < 4; ++ct)
        acc[rt][ct] = __builtin_amdgcn_mfma_f32_16x16x32_bf16(ah[rt], t[ct], acc[rt][ct], 0, 0, 0);
    __syncthreads();
  }

#pragma unroll
  for (int rt = 0; rt < 4; ++rt) {
    int row0 = rowBase + wr * 64 + rt * 16 + qd * 4;
#pragma unroll
    for (int ct = 0; ct < 4; ++ct) {
      int col = colBase + wc * 64 + ct * 16 + ln;
      float bb = bias[col];
      f32x4 a = acc[rt][ct];
#pragma unroll
      for (int r = 0; r < 4; ++r) {
        float val = a[r] + bb;
        if constexpr (OM == 0) {
          Ch[(size_t)(row0 + r) * 768 + col] = f2h(val);
        } else {
          Ch[(size_t)(row0 + r) * 768 + col] = f2b(val);
          Cl[(size_t)(row0 + r) * 768 + col] = f2h(val);
        }
      }
    }
  }
}

// =================================================================================
// sim2: P = exp(vp16*lp16^T - 20), single fp16 MFMA pass, 2-phase double-buffered
// glds staging (counted vmcnt(4), raw s_barrier). Fused bf16 row sums -> atomicAdd.
// =================================================================================
__global__ __launch_bounds__(256) void sim2_kernel(const short* __restrict__ vp,
                                                   const short* __restrict__ lp,
                                                   short* __restrict__ P,
                                                   float* __restrict__ S) {
  __shared__ alignas(16) short As[2][128 * 32];
  __shared__ alignas(16) short Bs[2][128 * 32];
  const int tid = threadIdx.x;
  int z, rowBase, colBase;
  xcd_decode(16, 16, 16, z, rowBase, colBase);
  const short* Az = vp + (size_t)z * 2048 * 768;
  const short* Bz = lp + (size_t)z * 2048 * 768;
  const int lane = tid & 63;
  const int ln = lane & 15;
  const int qd = lane >> 4;
  const int w = tid >> 6;
  const int wr = w >> 1, wc = w & 1;

  f32x4 acc[4][4];
#pragma unroll
  for (int i = 0; i < 4; ++i)
#pragma unroll
    for (int j = 0; j < 4; ++j) acc[i][j] = 0.f;

  auto stage = [&](int b, int kb) {
#pragma unroll
    for (int q = 0; q < 2; ++q) {
      int c = q * 256 + tid;
      int r = c >> 2;
      int k0 = ((c & 3) << 3) ^ swz(r);
      glds16(&Az[(size_t)(rowBase + r) * 768 + kb + k0], &As[b][c * 8]);
      glds16(&Bz[(size_t)(colBase + r) * 768 + kb + k0], &Bs[b][c * 8]);
    }
  };

  stage(0, 0);
  for (int kt = 0; kt < 24; ++kt) {
    const int cur = kt & 1;
    if (kt + 1 < 24) {
      stage(cur ^ 1, (kt + 1) * 32);  // next tile in flight across the barrier
      asm volatile("s_waitcnt vmcnt(4)" ::: "memory");  // current tile ready
    } else {
      asm volatile("s_waitcnt vmcnt(0)" ::: "memory");
    }
    asm volatile("s_barrier" ::: "memory");
    f16x8 af[4], bf[4];
#pragma unroll
    for (int rt = 0; rt < 4; ++rt) {
      int m = wr * 64 + rt * 16 + ln;
      af[rt] = *reinterpret_cast<const f16x8*>(&As[cur][m * 32 + ((qd * 8) ^ swz(m))]);
    }
#pragma unroll
    for (int ct = 0; ct < 4; ++ct) {
      int n = wc * 64 + ct * 16 + ln;
      bf[ct] = *reinterpret_cast<const f16x8*>(&Bs[cur][n * 32 + ((qd * 8) ^ swz(n))]);
    }
#pragma unroll
    for (int rt = 0; rt < 4; ++rt)
#pragma unroll
      for (int ct = 0; ct < 4; ++ct)
        acc[rt][ct] = __builtin_amdgcn_mfma_f32_16x16x32_f16(af[rt], bf[ct], acc[rt][ct], 0, 0, 0);
    asm volatile("s_waitcnt lgkmcnt(0)" ::: "memory");
    asm volatile("s_barrier" ::: "memory");  // buf[cur] free for overwrite next iter
  }

  short* Pz = P + (size_t)z * 2048 * 2048;
  float* Sz = S + (size_t)z * 2048;
#pragma unroll
  for (int rt = 0; rt < 4; ++rt) {
    int row0 = rowBase + wr * 64 + rt * 16 + qd * 4;
    float rowp[4] = {0.f, 0.f, 0.f, 0.f};
#pragma unroll
    for (int ct = 0; ct < 4; ++ct) {
      int col = colBase + wc * 64 + ct * 16 + ln;
      f32x4 a = acc[rt][ct];
#pragma unroll
      for (int r = 0; r < 4; ++r) {
        short h = f2b(__expf(a[r] - 20.0f));
        Pz[(size_t)(row0 + r) * 2048 + col] = h;
        rowp[r] += b2f(h);
      }
    }
#pragma unroll
    for (int r = 0; r < 4; ++r) {
      float v = rowp[r];
      v += __shfl_xor(v, 1);
      v += __shfl_xor(v, 2);
      v += __shfl_xor(v, 4);
      v += __shfl_xor(v, 8);
      if (ln == 0) atomicAdd(&Sz[row0 + r], v);
    }
  }
}

// =================================================================================
// gemm_k: C[m,n] = sum_k A[m,k]*B[n,k], bf16, both operands plain glds
// (pre-swizzled source), 2-phase double-buffered staging (counted vmcnt(4)).
// DUALA: A split 768|768.
// MODE 2: bf16 = acc*invL[row]; MODE 3: bf16 = acc; MODE 4: fp32 = acc+bias[col]
// =================================================================================
template <int MODE, bool DUALA>
__global__ __launch_bounds__(256) void gemm_k(const short* __restrict__ A,
                                              const short* __restrict__ A2,
                                              const short* __restrict__ B,
                                              void* __restrict__ C,
                                              const float* __restrict__ bias,
                                              const float* __restrict__ invL,
                                              int C_, int RSX_, int RPZ_,
                                              int K, int ldA, int ldB, int ldC,
                                              long sA, long sB, long sC, long sL) {
  __shared__ alignas(16) short As[2][128 * 32];
  __shared__ alignas(16) short Bs[2][128 * 32];
  const int tid = threadIdx.x;
  int z, rowBase, colBase;
  xcd_decode(C_, RSX_, RPZ_, z, rowBase, colBase);
  const short* Az = A + (size_t)z * sA;
  const short* Bz = B + (size_t)z * sB;
  const float* Lz = invL ? (invL + (size_t)z * sL) : nullptr;
  const int lane = tid & 63;
  const int ln = lane & 15;
  const int qd = lane >> 4;
  const int w = tid >> 6;
  const int wr = w >> 1, wc = w & 1;

  f32x4 acc[4][4];
#pragma unroll
  for (int i = 0; i < 4; ++i)
#pragma unroll
    for (int j = 0; j < 4; ++j) acc[i][j] = 0.f;

  auto stage = [&](int b, int kb) {
#pragma unroll
    for (int q = 0; q < 2; ++q) {
      int c = q * 256 + tid;
      int r = c >> 2;
      int k0 = ((c & 3) << 3) ^ swz(r);
      int kk = kb + k0;
      const short* src;
      if constexpr (DUALA) {
        src = (kk < 768) ? &Az[(size_t)(rowBase + r) * 768 + kk]
                         : &A2[(size_t)(rowBase + r) * 768 + kk - 768];
      } else {
        src = &Az[(size_t)(rowBase + r) * ldA + kk];
      }
      glds16(src, &As[b][c * 8]);
      glds16(&Bz[(size_t)(colBase + r) * ldB + kb + k0], &Bs[b][c * 8]);
    }
  };

  const int NT = K >> 5;
  stage(0, 0);
  for (int kt = 0; kt < NT; ++kt) {
    const int cur = kt & 1;
    if (kt + 1 < NT) {
      stage(cur ^ 1, (kt + 1) << 5);
      asm volatile("s_waitcnt vmcnt(4)" ::: "memory");
    } else {
      asm volatile("s_waitcnt vmcnt(0)" ::: "memory");
    }
    asm volatile("s_barrier" ::: "memory");
    bf16x8 af[4], bfv[4];
#pragma unroll
    for (int rt = 0; rt < 4; ++rt) {
      int m = wr * 64 + rt * 16 + ln;
      af[rt] = *reinterpret_cast<const bf16x8*>(&As[cur][m * 32 + ((qd * 8) ^ swz(m))]);
    }
#pragma unroll
    for (int ct = 0; ct < 4; ++ct) {
      int n = wc * 64 + ct * 16 + ln;
      bfv[ct] = *reinterpret_cast<const bf16x8*>(&Bs[cur][n * 32 + ((qd * 8) ^ swz(n))]);
    }
#pragma unroll
    for (int rt = 0; rt < 4; ++rt)
#pragma unroll
      for (int ct = 0; ct < 4; ++ct)
        acc[rt][ct] =
            __builtin_amdgcn_mfma_f32_16x16x32_bf16(af[rt], bfv[ct], acc[rt][ct], 0, 0, 0);
    asm volatile("s_waitcnt lgkmcnt(0)" ::: "memory");
    asm volatile("s_barrier" ::: "memory");
  }

#pragma unroll
  for (int rt = 0; rt < 4; ++rt) {
    int row0 = rowBase + wr * 64 + rt * 16 + qd * 4;
#pragma unroll
    for (int ct = 0; ct < 4; ++ct) {
      int col = colBase + wc * 64 + ct * 16 + ln;
      f32x4 a = acc[rt][ct];
      if constexpr (MODE == 2) {
        short* Co = (short*)C + (size_t)z * sC;
#pragma unroll
        for (int r = 0; r < 4; ++r)
          Co[(size_t)(row0 + r) * ldC + col] = f2b(a[r] * Lz[row0 + r]);
      } else if constexpr (MODE == 3) {
        short* Co = (short*)C + (size_t)z * sC;
#pragma unroll
        for (int r = 0; r < 4; ++r) Co[(size_t)(row0 + r) * ldC + col] = f2b(a[r]);
      } else {  // MODE 4
        float* Co = (float*)C + (size_t)z * sC;
        float bb = bias[col];
#pragma unroll
        for (int r = 0; r < 4; ++r) Co[(size_t)(row0 + r) * ldC + col] = a[r] + bb;
      }
    }
  }
}

extern "C" void kernel_launch(void* const* d_in, const int* in_sizes, int n_in,
                              void* d_out, int out_size, void* d_ws, size_t ws_size,
                              hipStream_t stream) {
  const float* vf = (const float*)d_in[0];
  const float* lf = (const float*)d_in[1];
  const float* Wv = (const float*)d_in[2];
  const float* bv = (const float*)d_in[3];
  const float* Wl = (const float*)d_in[4];
  const float* bl = (const float*)d_in[5];
  const float* Wo = (const float*)d_in[6];
  const float* bo = (const float*)d_in[7];

  constexpr int Bz = 8, L = 2048, D = 768, M = Bz * L, D2 = 2 * D;
  constexpr size_t PLANE = (size_t)M * D;      // 12,582,912 elems
  constexpr size_t WPLANE = (size_t)D * D;     // 589,824 elems

  char* wp = (char*)d_ws;
  auto alloc = [&](size_t bytes) {
    char* p = wp;
    wp += (bytes + 255) & ~(size_t)255;
    return p;
  };
  short* vp16  = (short*)alloc(PLANE * 2);               // 25.2 MB; -> av after xpose
  short* P     = (short*)alloc((size_t)Bz * L * L * 2);  // 67.1 MB; -> PT -> out_tmp
  float* invL  = (float*)alloc((size_t)M * 4);           // 64 KB
  float* sums  = (float*)alloc((size_t)M * 4);           // 64 KB

  // direct mode: lp planes in ws, final GEMM writes fp32 straight to d_out.
  size_t need_direct = (size_t)(wp - (char*)d_ws) + 2 * PLANE * 2 + 512;
  bool direct = ws_size >= need_direct;

  short *lp_bf, *lp16;
  if (direct) {
    lp_bf = (short*)alloc(PLANE * 2);
    lp16  = (short*)alloc(PLANE * 2);
  } else {
    lp_bf = (short*)d_out;
    lp16  = lp_bf + PLANE;
  }
  short* lpsT = lp16;    // lp16 dead after sim2
  short* vpT  = lp_bf;   // lp_bf dead after xpose<1> (step 4)
  short* av   = vp16;    // vp16 dead after xpose<0> (step 4b)
  short* al   = lp_bf;   // vpT dead after step 5; step 7 writes here
  // Wo bf16 planes live in the P region tail (PT dead after step 7):
  short* woh = P + 2 * PLANE;
  short* wol = woh + (size_t)D * D2;
  float* out_tmp = direct ? (float*)d_out : (float*)P;

  // Transient hi/lo planes inside the (not-yet-written) P region (55.0 <= 67.1 MB)
  short* fh  = P;
  short* fl  = P + PLANE;
  short* wvh = P + 2 * PLANE;
  short* wvl = wvh + WPLANE;
  short* wlh = wvl + WPLANE;
  short* wll = wlh + WPLANE;

  constexpr int GF  = (int)(PLANE / 8);           // 1,572,864 groups (feature)
  constexpr int GW  = (int)(WPLANE / 8);          // 73,728 groups (proj weight)
  constexpr int GWO = (int)((size_t)D * D2 / 8);  // 147,456 groups (Wo)

  // 0) zero the row-sum accumulator
  zero_kernel<<<dim3(M / 256), 256, 0, stream>>>(sums, M);

  // 1a) convert vision features + both proj weights (bf16 hi/lo for projg)
  cvt_kernel<<<dim3((GF + 2 * GW) / 256), 256, 0, stream>>>(
      vf, fh, fl, Wv, wvh, wvl, Wl, wlh, wll, GF, GW, GW);

  // 1b) vision projection -> vp16 (fp16)
  projg_kernel<0><<<dim3(768), 256, 0, stream>>>(fh, fl, wvh, wvl, bv, vp16, nullptr);

  // 1c) convert language features
  cvt_kernel<<<dim3(GF / 256), 256, 0, stream>>>(
      lf, fh, fl, nullptr, nullptr, nullptr, nullptr, nullptr, nullptr, GF, 0, 0);

  // 1d) language projection -> lp_bf (bf16) + lp16 (fp16)
  projg_kernel<1><<<dim3(768), 256, 0, stream>>>(fh, fl, wlh, wll, bl, lp_bf, lp16);

  // 2) P = exp(vp16*lp16^T - 20), fused row sums -> sums. 2048 blocks
  sim2_kernel<<<dim3(2048), 256, 0, stream>>>(vp16, lp16, P, sums);

  // 3) invL = 1/sums
  recip_kernel<<<dim3(M / 256), 256, 0, stream>>>(sums, invL, M);

  // 4) lpsT[z][d][i] = lp_bf[z][i][d] * invL  (-> lp16 slot)
  xpose_kernel<true><<<dim3(3072), 256, 0, stream>>>(lp_bf, invL, lpsT);

  // 4b) vpT[z][d][i] = bf16(vp16[z][i][d])    (-> lp_bf slot)
  xpose_kernel<false><<<dim3(3072), 256, 0, stream>>>(vp16, nullptr, vpT);

  // 5) aligned_vision = (P @ vp) * invL[row] -> av (vp16 slot). Both plain glds.
  gemm_k<2, false><<<dim3(768), 256, 0, stream>>>(
      P, nullptr, vpT, av, nullptr, invL, 6, 16, 16, L, L, L, D,
      (long)L * L, (long)D * L, (long)L * D, (long)L);

  // 6) P -> P^T in place (per z, 64x64 tile-pair swap). 8192 blocks
  transpose_inplace_kernel<<<dim3(8192), 256, 0, stream>>>(P);

  // 7) aligned_language = P^T @ lps -> al (lp_bf slot). Both plain glds.
  gemm_k<3, false><<<dim3(768), 256, 0, stream>>>(
      P, nullptr, lpsT, al, nullptr, nullptr, 6, 16, 16, L, L, L, D,
      (long)L * L, (long)D * L, (long)L * D, (long)L);

  // 8) convert Wo -> bf16 (P region tail; PT dead now)
  cvt_kernel<<<dim3(GWO / 256), 256, 0, stream>>>(
      Wo, woh, wol, nullptr, nullptr, nullptr, nullptr, nullptr, nullptr, GWO, 0, 0);

  // 9) out = [av | al] @ Wo^T + bo (fp32). B = woh plain bf16 glds.
  gemm_k<4, true><<<dim3(768), 256, 0, stream>>>(
      av, al, woh, out_tmp, bo, nullptr, 6, 16, 128, D2, D, D2, D, 0, 0, 0, 0);

  // 10) out_tmp -> d_out (only when step 9 couldn't write directly)
  if (!direct)
    hipMemcpyAsync(d_out, out_tmp, (size_t)M * D * 4, hipMemcpyDeviceToDevice, stream);
}